// Round 9
// baseline (527.376 us; speedup 1.0000x reference)
//
#include <hip/hip_runtime.h>
#include <hip/hip_bf16.h>

#define B_ 8
#define C_ 256
#define N_ 4096
#define D_ 16
#define TWO_C 512

#define NSLOT 10
#define SLOT_SHORTS 4128   // 128 rows * 32 m + 32-short pad (64 B) to stagger banks
#define SLOT_BYTES  (SLOT_SHORTS * 2)

typedef __bf16 bf16x8 __attribute__((ext_vector_type(8)));
typedef __bf16 bf16x4 __attribute__((ext_vector_type(4)));
typedef float f32x4 __attribute__((ext_vector_type(4)));
typedef unsigned short u16x4 __attribute__((ext_vector_type(4)));

static __device__ __forceinline__ unsigned short f2bf_rtn(float f) {
    unsigned int u = __builtin_bit_cast(unsigned int, f);
    u += 0x7fffu + ((u >> 16) & 1u);
    return (unsigned short)(u >> 16);
}

static __device__ __forceinline__ float bf2f(unsigned short s) {
    return __builtin_bit_cast(float, (unsigned int)s << 16);
}

__device__ __forceinline__ void gld16(const void* g, void* l) {
    __builtin_amdgcn_global_load_lds(
        (const __attribute__((address_space(1))) unsigned int*)g,
        (__attribute__((address_space(3))) unsigned int*)l, 16, 0, 0);
}

__device__ __forceinline__ f32x4 expv(f32x4 e) {
    f32x4 r = { __expf(e[0]), __expf(e[1]), __expf(e[2]), __expf(e[3]) };
    return r;
}

#define MF(K, Q) __builtin_amdgcn_mfma_f32_16x16x32_bf16((K), (Q), zerov, 0, 0, 0)

// ---------------------------------------------------------------------------
// Kernel 0: Wv1/Wv2 -> bf16 stacked [512][256]. grid = 64 blocks of 256.
// ---------------------------------------------------------------------------
__global__ __launch_bounds__(256) void wconv(
    const float* __restrict__ Wv1, const float* __restrict__ Wv2,
    unsigned short* __restrict__ Wbf)
{
    const int i = blockIdx.x * 256 + threadIdx.x;
    f32x4 a = ((const f32x4*)Wv1)[i];
    f32x4 b = ((const f32x4*)Wv2)[i];
    u16x4 ua = { f2bf_rtn(a[0]), f2bf_rtn(a[1]), f2bf_rtn(a[2]), f2bf_rtn(a[3]) };
    u16x4 ub = { f2bf_rtn(b[0]), f2bf_rtn(b[1]), f2bf_rtn(b[2]), f2bf_rtn(b[3]) };
    ((u16x4*)Wbf)[i] = ua;
    ((u16x4*)Wbf)[16384 + i] = ub;
}

// ---------------------------------------------------------------------------
// Kernel 1a: partial q/k over a 128-wide c-chunk + side-write x as bf16
// TRANSPOSED xbfT[b][n][512]. grid = B*16*4 = 512 blocks.
// ---------------------------------------------------------------------------
__global__ __launch_bounds__(256) void qk_part(
    const float* __restrict__ x1, const float* __restrict__ x2,
    const float* __restrict__ Wq, const float* __restrict__ Wk,
    float* __restrict__ pq, float* __restrict__ pk,
    unsigned short* __restrict__ xbfT)
{
    const int tid = threadIdx.x;
    const int bid = blockIdx.x;
    const int ch = bid & 3;
    const int nt = (bid >> 2) & 15;
    const int b  = bid >> 6;
    const int n  = nt * 256 + tid;

    const float* xs  = (ch < 2) ? x1 : x2;
    const int xoff = (ch & 1) * 128;
    const int wcol = ch * 128;

    const float* px = xs + ((size_t)b * C_ + xoff) * N_ + n;
    unsigned short* xT = xbfT + ((size_t)b * N_ + n) * TWO_C + wcol;

    float aq[D_], ak[D_];
#pragma unroll
    for (int d = 0; d < D_; ++d) { aq[d] = 0.f; ak[d] = 0.f; }

    for (int c8 = 0; c8 < 16; ++c8) {
        unsigned short xb[8];
#pragma unroll
        for (int j = 0; j < 8; ++j) {
            const int c = c8 * 8 + j;
            float xv = px[(size_t)c * N_];
            xb[j] = f2bf_rtn(xv);
#pragma unroll
            for (int d = 0; d < D_; ++d) {
                aq[d] += Wq[d * TWO_C + wcol + c] * xv;
                ak[d] += Wk[d * TWO_C + wcol + c] * xv;
            }
        }
        u16x4 lo = { xb[0], xb[1], xb[2], xb[3] };
        u16x4 hi = { xb[4], xb[5], xb[6], xb[7] };
        *(u16x4*)(xT + c8 * 8)     = lo;
        *(u16x4*)(xT + c8 * 8 + 4) = hi;
    }

    f32x4* q4 = (f32x4*)pq + (size_t)ch * B_ * N_ * 4 + ((size_t)b * N_ + n) * 4;
    f32x4* k4 = (f32x4*)pk + (size_t)ch * B_ * N_ * 4 + ((size_t)b * N_ + n) * 4;
#pragma unroll
    for (int j = 0; j < 4; ++j) {
        f32x4 tq = { aq[4*j], aq[4*j+1], aq[4*j+2], aq[4*j+3] };
        f32x4 tk = { ak[4*j], ak[4*j+1], ak[4*j+2], ak[4*j+3] };
        q4[j] = tq;
        k4[j] = tk;
    }
}

// ---------------------------------------------------------------------------
// Kernel 1b: reduce 4 partials + bias, emit bf16 q/k in [B][N][32] layout.
// ---------------------------------------------------------------------------
__global__ __launch_bounds__(256) void qk_reduce(
    const float* __restrict__ pq, const float* __restrict__ pk,
    const float* __restrict__ bq, const float* __restrict__ bk,
    unsigned short* __restrict__ qbf, unsigned short* __restrict__ kbf)
{
    const int tg = blockIdx.x * 256 + threadIdx.x;
    const int row = tg >> 2;
    const int d4  = tg & 3;
    const f32x4* pq4 = (const f32x4*)pq;
    const f32x4* pk4 = (const f32x4*)pk;
    f32x4 q = ((const f32x4*)bq)[d4];
    f32x4 k = ((const f32x4*)bk)[d4];
    const size_t stride = (size_t)B_ * N_ * 4;
#pragma unroll
    for (int ch = 0; ch < 4; ++ch) {
        q += pq4[ch * stride + tg];
        k += pk4[ch * stride + tg];
    }
    u16x4 qo = { f2bf_rtn(q[0]), f2bf_rtn(q[1]), f2bf_rtn(q[2]), f2bf_rtn(q[3]) };
    u16x4 ko = { f2bf_rtn(k[0]), f2bf_rtn(k[1]), f2bf_rtn(k[2]), f2bf_rtn(k[3]) };
    u16x4 z  = { 0, 0, 0, 0 };
    *(u16x4*)(qbf + (size_t)row * 32 + d4 * 4)      = qo;
    *(u16x4*)(qbf + (size_t)row * 32 + 16 + d4 * 4) = z;
    *(u16x4*)(kbf + (size_t)row * 32 + d4 * 4)      = ko;
    *(u16x4*)(kbf + (size_t)row * 32 + 16 + d4 * 4) = z;
}

// ---------------------------------------------------------------------------
// Kernel 2: v = Wv @ x + bv via MFMA, LDS-free. grid = 1024 blocks of 256.
// ---------------------------------------------------------------------------
__global__ __launch_bounds__(256) void v_mfma(
    const unsigned short* __restrict__ Wbf,
    const unsigned short* __restrict__ xbfT,
    const float* __restrict__ bv1, const float* __restrict__ bv2,
    unsigned short* __restrict__ vstack)
{
    const int tid  = threadIdx.x;
    const int lane = tid & 63;
    const int wid  = tid >> 6;
    const int bid  = blockIdx.x;
    const int b    = bid >> 7;
    const int half = (bid >> 6) & 1;
    const int n0   = (bid & 63) * 64;
    const int col  = lane & 15;
    const int grp  = lane >> 4;
    const int koff = grp * 8;

    const unsigned short* pa[4];
    const unsigned short* pb[4];
#pragma unroll
    for (int ai = 0; ai < 4; ++ai)
        pa[ai] = Wbf + (size_t)(half * 256 + wid * 64 + ai * 16 + col) * 256 + koff;
#pragma unroll
    for (int bj = 0; bj < 4; ++bj)
        pb[bj] = xbfT + ((size_t)b * N_ + n0 + bj * 16 + col) * TWO_C + half * 256 + koff;

    f32x4 acc[4][4];
#pragma unroll
    for (int ai = 0; ai < 4; ++ai)
#pragma unroll
        for (int bj = 0; bj < 4; ++bj)
            acc[ai][bj] = (f32x4){0.f, 0.f, 0.f, 0.f};

#pragma unroll
    for (int s = 0; s < 8; ++s) {
        bf16x8 af[4], bfr[4];
#pragma unroll
        for (int ai = 0; ai < 4; ++ai) af[ai] = *(const bf16x8*)(pa[ai] + s * 32);
#pragma unroll
        for (int bj = 0; bj < 4; ++bj) bfr[bj] = *(const bf16x8*)(pb[bj] + s * 32);
#pragma unroll
        for (int ai = 0; ai < 4; ++ai)
#pragma unroll
            for (int bj = 0; bj < 4; ++bj)
                acc[ai][bj] = __builtin_amdgcn_mfma_f32_16x16x32_bf16(
                    af[ai], bfr[bj], acc[ai][bj], 0, 0, 0);
    }

    const float* bias = half ? bv2 : bv1;
#pragma unroll
    for (int ai = 0; ai < 4; ++ai) {
        const int cb = wid * 64 + ai * 16 + grp * 4;
#pragma unroll
        for (int r = 0; r < 4; ++r) {
            const float bv = bias[cb + r];
            unsigned short* vr = vstack + ((size_t)b * 512 + half * 256 + cb + r) * N_;
#pragma unroll
            for (int bj = 0; bj < 4; ++bj)
                vr[n0 + bj * 16 + col] = f2bf_rtn(acc[ai][bj][r] + bv);
        }
    }
}

// ---------------------------------------------------------------------------
// Kernel 2b: rowsum -> sinvbuf[b*N+n] = 1/sum_m exp(e[n][m]).
// grid = B*64 = 512 blocks of 256 (4 waves, wave owns 16 n-rows).
// ---------------------------------------------------------------------------
__global__ __launch_bounds__(256) void rowsum(
    const unsigned short* __restrict__ qbf,
    const unsigned short* __restrict__ kbf,
    float* __restrict__ sinvbuf)
{
    const int tid  = threadIdx.x;
    const int lane = tid & 63;
    const int wid  = tid >> 6;
    const int b  = blockIdx.x >> 6;
    const int n0 = (blockIdx.x & 63) * 64 + wid * 16;
    const int col = lane & 15;
    const int grp = lane >> 4;
    const f32x4 zerov = {0.f, 0.f, 0.f, 0.f};

    const bf16x8 qf = *(const bf16x8*)(qbf + ((size_t)b * N_ + n0 + col) * 32 + grp * 8);
    const unsigned short* kp = kbf + ((size_t)b * N_ + col) * 32 + grp * 8;

    float rs = 0.f;
#pragma unroll 4
    for (int t = 0; t < 128; ++t) {
        bf16x8 k0 = *(const bf16x8*)kp;
        bf16x8 k1 = *(const bf16x8*)(kp + 512);
        kp += 1024;
        f32x4 p0 = expv(MF(k0, qf));
        f32x4 p1 = expv(MF(k1, qf));
        rs += (p0[0] + p0[1]) + (p0[2] + p0[3])
            + (p1[0] + p1[1]) + (p1[2] + p1[3]);
    }
    rs += __shfl_xor(rs, 16);
    rs += __shfl_xor(rs, 32);
    if (lane < 16)
        sinvbuf[(size_t)b * N_ + n0 + col] = 1.f / rs;
}

// ---------------------------------------------------------------------------
// Kernel 3: FUSED attention + PV with 10-slot P-ring and 1KB-contiguous
// deferred att flushes.
// Tile: 256c (ct half of stacked V) x 128n; 512 thr = 8 waves (2M x 4N).
// P-tiles live in a 10-slot LDS ring (tile T -> slot T%10; 8-flush window +
// produce-ahead are 9 consecutive tiles = distinct mod 10 -> race-free).
// Every 8 steps (when this ct owns the m-half), each wave flushes 8 tiles x
// its 16 rows: LDS readback (un-swizzled) -> bf16->f32 -> *inv -> ONE 1KB
// contiguous store per row per instruction (64 lanes x 16B).
// Fences: vmcnt(2) normal steps (drains gld16 pair), vmcnt(18) flush steps
// (2 carryover k + 2 gld16 + 2 k + 16 stores -> drains through gld16s).
// grid = 512 (8b x 32nt x 2ct interleaved), 1 block/CU (115 KB LDS).
// ---------------------------------------------------------------------------
__global__ __launch_bounds__(512) void fused_pv(
    const unsigned short* __restrict__ qbf,
    const unsigned short* __restrict__ kbf,
    const unsigned short* __restrict__ vstack,
    const float* __restrict__ sinvbuf,
    const float* __restrict__ x1, const float* __restrict__ x2,
    float* __restrict__ out1, float* __restrict__ out2,
    float* __restrict__ att)
{
    __shared__ unsigned short Asm[2][256 * 32];          // 32 KB, V dbuf
    __shared__ unsigned short Bring[NSLOT * SLOT_SHORTS]; // 82.5 KB, P ring
    __shared__ float sinvLds[128];

    const int tid  = threadIdx.x;
    const int lane = tid & 63;
    const int wid  = tid >> 6;
    const int wr   = wid >> 2;      // 0..1 : c-offset *128
    const int wc   = wid & 3;       // 0..3 : n-offset *32
    const int col  = lane & 15;
    const int grp  = lane >> 4;

    // XCD swizzle: 64 blocks/XCD = one batch; ct interleaved so both
    // scheduling waves mix store halves.
    const int bid  = blockIdx.x;
    const int orig = (bid & 7) * 64 + (bid >> 3);
    const int b   = orig >> 6;
    const int idx = orig & 63;
    const int ct  = idx & 1;
    const int nt  = idx >> 1;
    const int n0  = nt * 128;

    const f32x4 zerov = {0.f, 0.f, 0.f, 0.f};

    // E row owned by this thread
    const int nl = wid * 16 + col;
    if (tid < 128) sinvLds[tid] = sinvbuf[(size_t)b * N_ + n0 + tid];

    const bf16x8 qf = *(const bf16x8*)(qbf + ((size_t)b * N_ + n0 + nl) * 32 + grp * 8);
    const unsigned short* kbase = kbf + ((size_t)b * N_ + col) * 32 + grp * 8;

    // A (V) staging: pre-swizzled global source, linear LDS dest
    const unsigned short* Vb = vstack + ((size_t)b * 512 + ct * 256) * N_;
    const int q1 = tid + 512;
    const unsigned short* pa0 = Vb + (size_t)(tid >> 2) * N_ + (((tid & 3) ^ ((tid >> 2) & 3)) * 8);
    const unsigned short* pa1 = Vb + (size_t)(q1 >> 2) * N_ + (((q1 & 3) ^ ((q1 >> 2) & 3)) * 8);

    // P write byte-offsets within a ring slot (XOR-swizzled per 16B unit)
    const int bwA = nl * 64 + ((((grp >> 1)) ^ (col & 3)) << 4) + (grp & 1) * 8;
    const int bwB = bwA ^ 32;

    // fragment read byte-offsets
    const int raBase = (wr * 128 + col) * 64 + ((grp ^ (col & 3)) << 4);
    const int rbBase = (wc * 32  + col) * 64 + ((grp ^ (col & 3)) << 4);

    // flush lane constants: lane covers tile fj, within-tile m = fu*8+fh*4..+3
    const int fj = lane >> 3;
    const int fu = (lane >> 1) & 3;
    const int fh = lane & 1;
    float* const attRow0 = att + (size_t)b * N_ * N_ + (size_t)n0 * N_ + lane * 4;

    f32x4 acc[8][2];
#pragma unroll
    for (int ai = 0; ai < 8; ++ai)
#pragma unroll
        for (int bj = 0; bj < 2; ++bj)
            acc[ai][bj] = zerov;

#define PACKB(P, BASE, OFF) do {                                              \
    bf16x4 pkv = { (__bf16)(P)[0], (__bf16)(P)[1],                            \
                   (__bf16)(P)[2], (__bf16)(P)[3] };                          \
    *(bf16x4*)((char*)(BASE) + (OFF)) = pkv;                                  \
} while (0)

    // ---- prologue: stage A(0); produce tile 0 -> slot 0; prefetch k(1) ----
    gld16(pa0, &Asm[0][tid * 8]);
    gld16(pa1, &Asm[0][tid * 8 + 4096]);
    pa0 += 32; pa1 += 32;
    __builtin_amdgcn_sched_barrier(0);
    bf16x8 kA0, kA1, kB0, kB1;
    const unsigned short* kp = kbase;
    {
        bf16x8 k0 = *(const bf16x8*)kp;
        bf16x8 k1 = *(const bf16x8*)(kp + 512);
        kp += 1024;
        f32x4 p0 = expv(MF(k0, qf));
        f32x4 p1 = expv(MF(k1, qf));
        kB0 = *(const bf16x8*)kp;          // k(tile 1)
        kB1 = *(const bf16x8*)(kp + 512);
        kp += 1024;
        PACKB(p0, Bring, bwA);
        PACKB(p1, Bring, bwB);
    }
    asm volatile("s_waitcnt vmcnt(2) lgkmcnt(0)" ::: "memory");
    __builtin_amdgcn_s_barrier();
    __builtin_amdgcn_sched_barrier(0);

    auto step = [&](const unsigned short* AsCur, unsigned short* AsNxt,
                    const unsigned short* BsCur, unsigned short* BsNxt,
                    const bf16x8& kc0, const bf16x8& kc1,
                    bf16x8& kn0, bf16x8& kn1, bool doNext,
                    bool doFlush, int f, int fb) {
        // (1) PV fragment reads for this step
        bf16x8 bfr[2], af0[4], af1[4];
#pragma unroll
        for (int bj = 0; bj < 2; ++bj)
            bfr[bj] = *(const bf16x8*)((const char*)BsCur + rbBase + bj * 1024);
#pragma unroll
        for (int ai = 0; ai < 4; ++ai)
            af0[ai] = *(const bf16x8*)((const char*)AsCur + raBase + ai * 1024);
        // (2) stage A(next) — pinned first in vmem queue
        if (doNext) {
            gld16(pa0, AsNxt + tid * 8);
            gld16(pa1, AsNxt + tid * 8 + 4096);
            pa0 += 32; pa1 += 32;
        }
        __builtin_amdgcn_sched_barrier(0);
        // (3) produce P(next) -> ring; prefetch k(next+1)
        if (doNext) {
            f32x4 e0 = MF(kc0, qf);
            f32x4 e1 = MF(kc1, qf);
            kn0 = *(const bf16x8*)kp;
            kn1 = *(const bf16x8*)(kp + 512);
            kp += 1024;
            f32x4 p0 = expv(e0);
            f32x4 p1 = expv(e1);
            PACKB(p0, BsNxt, bwA);
            PACKB(p1, BsNxt, bwB);
        }
        // (3b) flush: 8 tiles x 16 rows, 1KB contiguous per row
        if (doFlush) {
            int sl = fb + fj; if (sl >= NSLOT) sl -= NSLOT;
            const char* lbase = (const char*)Bring + sl * SLOT_BYTES;
            float* gbase = attRow0 + (size_t)f * 256;
#pragma unroll
            for (int i = 0; i < 16; ++i) {
                const int r = wid * 16 + i;
                u16x4 pb = *(const u16x4*)(lbase + r * 64 + ((fu ^ (i & 3)) << 4) + fh * 8);
                const float iv = sinvLds[r];
                f32x4 pv = { bf2f(pb[0]) * iv, bf2f(pb[1]) * iv,
                             bf2f(pb[2]) * iv, bf2f(pb[3]) * iv };
                *(f32x4*)(gbase + (size_t)r * N_) = pv;
            }
        }
        // (4) PV MFMAs
#pragma unroll
        for (int ai = 0; ai < 4; ++ai)
#pragma unroll
            for (int bj = 0; bj < 2; ++bj)
                acc[ai][bj] = __builtin_amdgcn_mfma_f32_16x16x32_bf16(
                    af0[ai], bfr[bj], acc[ai][bj], 0, 0, 0);
#pragma unroll
        for (int ai = 0; ai < 4; ++ai)
            af1[ai] = *(const bf16x8*)((const char*)AsCur + raBase + (4 + ai) * 1024);
#pragma unroll
        for (int ai = 0; ai < 4; ++ai)
#pragma unroll
            for (int bj = 0; bj < 2; ++bj)
                acc[4 + ai][bj] = __builtin_amdgcn_mfma_f32_16x16x32_bf16(
                    af1[ai], bfr[bj], acc[4 + ai][bj], 0, 0, 0);
        // (5) fence
        if (doNext || doFlush) {
            if (doFlush) asm volatile("s_waitcnt vmcnt(18) lgkmcnt(0)" ::: "memory");
            else         asm volatile("s_waitcnt vmcnt(2) lgkmcnt(0)" ::: "memory");
            __builtin_amdgcn_s_barrier();
            __builtin_amdgcn_sched_barrier(0);
        }
    };

    int slotCur = 0, slotNxt = 1;
    int fbase = 0;
    for (int tt = 0; tt < 64; ++tt) {
        // step T = 2tt : PV tile 2tt, produce tile 2tt+1
        step(&Asm[0][0], &Asm[1][0],
             Bring + slotCur * SLOT_SHORTS, Bring + slotNxt * SLOT_SHORTS,
             kB0, kB1, kA0, kA1, true, false, 0, 0);
        slotCur = slotNxt; slotNxt = (slotNxt + 1 == NSLOT) ? 0 : slotNxt + 1;

        // step T = 2tt+1 : PV tile 2tt+1, produce tile 2tt+2, maybe flush
        const bool fl = ((tt & 3) == 3) && ((tt >> 5) == ct);
        step(&Asm[1][0], &Asm[0][0],
             Bring + slotCur * SLOT_SHORTS, Bring + slotNxt * SLOT_SHORTS,
             kA0, kA1, kB0, kB1, tt < 63, fl, tt >> 2, fbase);
        slotCur = slotNxt; slotNxt = (slotNxt + 1 == NSLOT) ? 0 : slotNxt + 1;
        if ((tt & 3) == 3) { fbase += 8; if (fbase >= NSLOT) fbase -= NSLOT; }
    }

    // ---- epilogue: out = acc * inv + x ----
    float* outp     = ct ? out2 : out1;
    const float* xp = ct ? x2 : x1;
    float sc[2];
#pragma unroll
    for (int bj = 0; bj < 2; ++bj)
        sc[bj] = sinvLds[wc * 32 + bj * 16 + col];
#pragma unroll
    for (int ai = 0; ai < 8; ++ai) {
        const int c_l = wr * 128 + ai * 16 + grp * 4;
#pragma unroll
        for (int bj = 0; bj < 2; ++bj) {
            const int n = n0 + wc * 32 + bj * 16 + col;
#pragma unroll
            for (int r = 0; r < 4; ++r) {
                const size_t idx = ((size_t)b * C_ + c_l + r) * N_ + n;
                outp[idx] = acc[ai][bj][r] * sc[bj] + xp[idx];
            }
        }
    }
#undef PACKB
}

// ---------------------------------------------------------------------------
extern "C" void kernel_launch(void* const* d_in, const int* in_sizes, int n_in,
                              void* d_out, int out_size, void* d_ws, size_t ws_size,
                              hipStream_t stream)
{
    const float* x1  = (const float*)d_in[0];
    const float* x2  = (const float*)d_in[1];
    const float* Wq  = (const float*)d_in[2];
    const float* bq  = (const float*)d_in[3];
    const float* Wk  = (const float*)d_in[4];
    const float* bk  = (const float*)d_in[5];
    const float* Wv1 = (const float*)d_in[6];
    const float* bv1 = (const float*)d_in[7];
    const float* Wv2 = (const float*)d_in[8];
    const float* bv2 = (const float*)d_in[9];

    float* out  = (float*)d_out;
    float* out1 = out;
    float* out2 = out + (size_t)B_ * C_ * N_;
    float* att  = out + 2 * (size_t)B_ * C_ * N_;

    // xbfT (32 MB) scribbles the front of the att region; fused_pv
    // fully overwrites all of att afterwards.
    unsigned short* xbfT = (unsigned short*)att;

    char* ws = (char*)d_ws;
    unsigned short* qbf = (unsigned short*)ws;                                  // 2 MB
    unsigned short* kbf = (unsigned short*)(ws + (size_t)2 * 1024 * 1024);      // 2 MB
    unsigned short* vstack = (unsigned short*)(ws + (size_t)4 * 1024 * 1024);   // 32 MB
    float* pq = (float*)(ws + (size_t)36 * 1024 * 1024);                        // 8 MB
    float* pk = (float*)(ws + (size_t)44 * 1024 * 1024);                        // 8 MB
    unsigned short* Wbf = (unsigned short*)(ws + (size_t)52 * 1024 * 1024);     // 256 KB
    float* sinvbuf = (float*)(ws + (size_t)53 * 1024 * 1024);                   // 128 KB

    wconv<<<64, 256, 0, stream>>>(Wv1, Wv2, Wbf);
    qk_part<<<B_ * 16 * 4, 256, 0, stream>>>(x1, x2, Wq, Wk, pq, pk, xbfT);
    qk_reduce<<<(B_ * N_ * 4) / 256, 256, 0, stream>>>(pq, pk, bq, bk, qbf, kbf);
    rowsum<<<B_ * 64, 256, 0, stream>>>(qbf, kbf, sinvbuf);
    v_mfma<<<B_ * 2 * 64, 256, 0, stream>>>(Wbf, xbfT, bv1, bv2, vstack);
    fused_pv<<<512, 512, 0, stream>>>(qbf, kbf, vstack, sinvbuf, x1, x2, out1, out2, att);
}

// Round 10
// 507.132 us; speedup vs baseline: 1.0399x; 1.0399x over previous
//
#include <hip/hip_runtime.h>
#include <hip/hip_bf16.h>

#define B_ 8
#define C_ 256
#define N_ 4096
#define D_ 16
#define TWO_C 512

#define PSLOT_SHORTS 4128   // 128 rows * 32 m + 32-short pad
#define PSLOT_BYTES  (PSLOT_SHORTS * 2)

typedef __bf16 bf16x8 __attribute__((ext_vector_type(8)));
typedef __bf16 bf16x4 __attribute__((ext_vector_type(4)));
typedef float f32x4 __attribute__((ext_vector_type(4)));
typedef unsigned short u16x4 __attribute__((ext_vector_type(4)));

static __device__ __forceinline__ unsigned short f2bf_rtn(float f) {
    unsigned int u = __builtin_bit_cast(unsigned int, f);
    u += 0x7fffu + ((u >> 16) & 1u);
    return (unsigned short)(u >> 16);
}

static __device__ __forceinline__ float bf2f(unsigned short s) {
    return __builtin_bit_cast(float, (unsigned int)s << 16);
}

__device__ __forceinline__ void gld16(const void* g, void* l) {
    __builtin_amdgcn_global_load_lds(
        (const __attribute__((address_space(1))) unsigned int*)g,
        (__attribute__((address_space(3))) unsigned int*)l, 16, 0, 0);
}

__device__ __forceinline__ f32x4 expv(f32x4 e) {
    f32x4 r = { __expf(e[0]), __expf(e[1]), __expf(e[2]), __expf(e[3]) };
    return r;
}

#define MF(K, Q) __builtin_amdgcn_mfma_f32_16x16x32_bf16((K), (Q), zerov, 0, 0, 0)

// ---------------------------------------------------------------------------
// Kernel 0: Wv1/Wv2 -> bf16 stacked [512][256]. grid = 64 blocks of 256.
// ---------------------------------------------------------------------------
__global__ __launch_bounds__(256) void wconv(
    const float* __restrict__ Wv1, const float* __restrict__ Wv2,
    unsigned short* __restrict__ Wbf)
{
    const int i = blockIdx.x * 256 + threadIdx.x;
    f32x4 a = ((const f32x4*)Wv1)[i];
    f32x4 b = ((const f32x4*)Wv2)[i];
    u16x4 ua = { f2bf_rtn(a[0]), f2bf_rtn(a[1]), f2bf_rtn(a[2]), f2bf_rtn(a[3]) };
    u16x4 ub = { f2bf_rtn(b[0]), f2bf_rtn(b[1]), f2bf_rtn(b[2]), f2bf_rtn(b[3]) };
    ((u16x4*)Wbf)[i] = ua;
    ((u16x4*)Wbf)[16384 + i] = ub;
}

// ---------------------------------------------------------------------------
// Kernel 1a: partial q/k over a 128-wide c-chunk + side-write x as bf16
// TRANSPOSED xbfT[b][n][512]. grid = B*16*4 = 512 blocks.
// ---------------------------------------------------------------------------
__global__ __launch_bounds__(256) void qk_part(
    const float* __restrict__ x1, const float* __restrict__ x2,
    const float* __restrict__ Wq, const float* __restrict__ Wk,
    float* __restrict__ pq, float* __restrict__ pk,
    unsigned short* __restrict__ xbfT)
{
    const int tid = threadIdx.x;
    const int bid = blockIdx.x;
    const int ch = bid & 3;
    const int nt = (bid >> 2) & 15;
    const int b  = bid >> 6;
    const int n  = nt * 256 + tid;

    const float* xs  = (ch < 2) ? x1 : x2;
    const int xoff = (ch & 1) * 128;
    const int wcol = ch * 128;

    const float* px = xs + ((size_t)b * C_ + xoff) * N_ + n;
    unsigned short* xT = xbfT + ((size_t)b * N_ + n) * TWO_C + wcol;

    float aq[D_], ak[D_];
#pragma unroll
    for (int d = 0; d < D_; ++d) { aq[d] = 0.f; ak[d] = 0.f; }

    for (int c8 = 0; c8 < 16; ++c8) {
        unsigned short xb[8];
#pragma unroll
        for (int j = 0; j < 8; ++j) {
            const int c = c8 * 8 + j;
            float xv = px[(size_t)c * N_];
            xb[j] = f2bf_rtn(xv);
#pragma unroll
            for (int d = 0; d < D_; ++d) {
                aq[d] += Wq[d * TWO_C + wcol + c] * xv;
                ak[d] += Wk[d * TWO_C + wcol + c] * xv;
            }
        }
        u16x4 lo = { xb[0], xb[1], xb[2], xb[3] };
        u16x4 hi = { xb[4], xb[5], xb[6], xb[7] };
        *(u16x4*)(xT + c8 * 8)     = lo;
        *(u16x4*)(xT + c8 * 8 + 4) = hi;
    }

    f32x4* q4 = (f32x4*)pq + (size_t)ch * B_ * N_ * 4 + ((size_t)b * N_ + n) * 4;
    f32x4* k4 = (f32x4*)pk + (size_t)ch * B_ * N_ * 4 + ((size_t)b * N_ + n) * 4;
#pragma unroll
    for (int j = 0; j < 4; ++j) {
        f32x4 tq = { aq[4*j], aq[4*j+1], aq[4*j+2], aq[4*j+3] };
        f32x4 tk = { ak[4*j], ak[4*j+1], ak[4*j+2], ak[4*j+3] };
        q4[j] = tq;
        k4[j] = tk;
    }
}

// ---------------------------------------------------------------------------
// Kernel 1b: reduce 4 partials + bias, emit bf16 q/k in [B][N][32] layout.
// ---------------------------------------------------------------------------
__global__ __launch_bounds__(256) void qk_reduce(
    const float* __restrict__ pq, const float* __restrict__ pk,
    const float* __restrict__ bq, const float* __restrict__ bk,
    unsigned short* __restrict__ qbf, unsigned short* __restrict__ kbf)
{
    const int tg = blockIdx.x * 256 + threadIdx.x;
    const int row = tg >> 2;
    const int d4  = tg & 3;
    const f32x4* pq4 = (const f32x4*)pq;
    const f32x4* pk4 = (const f32x4*)pk;
    f32x4 q = ((const f32x4*)bq)[d4];
    f32x4 k = ((const f32x4*)bk)[d4];
    const size_t stride = (size_t)B_ * N_ * 4;
#pragma unroll
    for (int ch = 0; ch < 4; ++ch) {
        q += pq4[ch * stride + tg];
        k += pk4[ch * stride + tg];
    }
    u16x4 qo = { f2bf_rtn(q[0]), f2bf_rtn(q[1]), f2bf_rtn(q[2]), f2bf_rtn(q[3]) };
    u16x4 ko = { f2bf_rtn(k[0]), f2bf_rtn(k[1]), f2bf_rtn(k[2]), f2bf_rtn(k[3]) };
    u16x4 z  = { 0, 0, 0, 0 };
    *(u16x4*)(qbf + (size_t)row * 32 + d4 * 4)      = qo;
    *(u16x4*)(qbf + (size_t)row * 32 + 16 + d4 * 4) = z;
    *(u16x4*)(kbf + (size_t)row * 32 + d4 * 4)      = ko;
    *(u16x4*)(kbf + (size_t)row * 32 + 16 + d4 * 4) = z;
}

// ---------------------------------------------------------------------------
// Kernel 2: v = Wv @ x + bv via MFMA, LDS-free. grid = 1024 blocks of 256.
// ---------------------------------------------------------------------------
__global__ __launch_bounds__(256) void v_mfma(
    const unsigned short* __restrict__ Wbf,
    const unsigned short* __restrict__ xbfT,
    const float* __restrict__ bv1, const float* __restrict__ bv2,
    unsigned short* __restrict__ vstack)
{
    const int tid  = threadIdx.x;
    const int lane = tid & 63;
    const int wid  = tid >> 6;
    const int bid  = blockIdx.x;
    const int b    = bid >> 7;
    const int half = (bid >> 6) & 1;
    const int n0   = (bid & 63) * 64;
    const int col  = lane & 15;
    const int grp  = lane >> 4;
    const int koff = grp * 8;

    const unsigned short* pa[4];
    const unsigned short* pb[4];
#pragma unroll
    for (int ai = 0; ai < 4; ++ai)
        pa[ai] = Wbf + (size_t)(half * 256 + wid * 64 + ai * 16 + col) * 256 + koff;
#pragma unroll
    for (int bj = 0; bj < 4; ++bj)
        pb[bj] = xbfT + ((size_t)b * N_ + n0 + bj * 16 + col) * TWO_C + half * 256 + koff;

    f32x4 acc[4][4];
#pragma unroll
    for (int ai = 0; ai < 4; ++ai)
#pragma unroll
        for (int bj = 0; bj < 4; ++bj)
            acc[ai][bj] = (f32x4){0.f, 0.f, 0.f, 0.f};

#pragma unroll
    for (int s = 0; s < 8; ++s) {
        bf16x8 af[4], bfr[4];
#pragma unroll
        for (int ai = 0; ai < 4; ++ai) af[ai] = *(const bf16x8*)(pa[ai] + s * 32);
#pragma unroll
        for (int bj = 0; bj < 4; ++bj) bfr[bj] = *(const bf16x8*)(pb[bj] + s * 32);
#pragma unroll
        for (int ai = 0; ai < 4; ++ai)
#pragma unroll
            for (int bj = 0; bj < 4; ++bj)
                acc[ai][bj] = __builtin_amdgcn_mfma_f32_16x16x32_bf16(
                    af[ai], bfr[bj], acc[ai][bj], 0, 0, 0);
    }

    const float* bias = half ? bv2 : bv1;
#pragma unroll
    for (int ai = 0; ai < 4; ++ai) {
        const int cb = wid * 64 + ai * 16 + grp * 4;
#pragma unroll
        for (int r = 0; r < 4; ++r) {
            const float bv = bias[cb + r];
            unsigned short* vr = vstack + ((size_t)b * 512 + half * 256 + cb + r) * N_;
#pragma unroll
            for (int bj = 0; bj < 4; ++bj)
                vr[n0 + bj * 16 + col] = f2bf_rtn(acc[ai][bj][r] + bv);
        }
    }
}

// ---------------------------------------------------------------------------
// Kernel 2b: rowsum -> sinvbuf[b*N+n] = 1/sum_m exp(e[n][m]).
// grid = B*64 = 512 blocks of 256.
// ---------------------------------------------------------------------------
__global__ __launch_bounds__(256) void rowsum(
    const unsigned short* __restrict__ qbf,
    const unsigned short* __restrict__ kbf,
    float* __restrict__ sinvbuf)
{
    const int tid  = threadIdx.x;
    const int lane = tid & 63;
    const int wid  = tid >> 6;
    const int b  = blockIdx.x >> 6;
    const int n0 = (blockIdx.x & 63) * 64 + wid * 16;
    const int col = lane & 15;
    const int grp = lane >> 4;
    const f32x4 zerov = {0.f, 0.f, 0.f, 0.f};

    const bf16x8 qf = *(const bf16x8*)(qbf + ((size_t)b * N_ + n0 + col) * 32 + grp * 8);
    const unsigned short* kp = kbf + ((size_t)b * N_ + col) * 32 + grp * 8;

    float rs = 0.f;
#pragma unroll 4
    for (int t = 0; t < 128; ++t) {
        bf16x8 k0 = *(const bf16x8*)kp;
        bf16x8 k1 = *(const bf16x8*)(kp + 512);
        kp += 1024;
        f32x4 p0 = expv(MF(k0, qf));
        f32x4 p1 = expv(MF(k1, qf));
        rs += (p0[0] + p0[1]) + (p0[2] + p0[3])
            + (p1[0] + p1[1]) + (p1[2] + p1[3]);
    }
    rs += __shfl_xor(rs, 16);
    rs += __shfl_xor(rs, 32);
    if (lane < 16)
        sinvbuf[(size_t)b * N_ + n0 + col] = 1.f / rs;
}

// ---------------------------------------------------------------------------
// Kernel 3: FUSED attention + PV. Store-concurrency-first schedule:
//  - 3-slot A ring, D=2 prefetch (gld16 for tile T+2 issued at step T).
//    g(T+1) retirement is piggybacked on the compiler's wait for the
//    k(T+1) register consume at step T (g issued before k at T-1, FIFO)
//    -> the end-of-step fence is ONLY lgkmcnt(0)+barrier, NO vmcnt:
//    att stores are never force-drained (live ~2 steps, ~3/wave in flight).
//  - 3-slot P ring: produce P(T+1) / consume P(T) / flush P(T-1) per step.
//  - uniform 1 store/wave/step: ct splits att n-rows (64 each); wave w
//    flushes rows ct*64+w*8..+8 of tile T-1 = one 1KB contiguous store.
//  - LDS 73 KB -> 2 blocks/CU (16 waves/CU) for cross-block overlap.
// Steps 126/127 clamp (redundant re-stage/store of tile 127 - idempotent).
// grid = 512 (8b x 32nt x 2ct, one batch per XCD), 512 threads.
// ---------------------------------------------------------------------------
__global__ __launch_bounds__(512) void fused_pv(
    const unsigned short* __restrict__ qbf,
    const unsigned short* __restrict__ kbf,
    const unsigned short* __restrict__ vstack,
    const float* __restrict__ sinvbuf,
    const float* __restrict__ x1, const float* __restrict__ x2,
    float* __restrict__ out1, float* __restrict__ out2,
    float* __restrict__ att)
{
    __shared__ unsigned short AsmR[3][256 * 32];       // 48 KB, V ring
    __shared__ unsigned short Bring[3][PSLOT_SHORTS];  // 24.2 KB, P ring
    __shared__ float sinvLds[128];

    const int tid  = threadIdx.x;
    const int lane = tid & 63;
    const int wid  = tid >> 6;
    const int wr   = wid >> 2;      // 0..1 : c-offset *128
    const int wc   = wid & 3;       // 0..3 : n-offset *32
    const int col  = lane & 15;
    const int grp  = lane >> 4;

    // XCD swizzle: 64 blocks/XCD = one batch
    const int bid  = blockIdx.x;
    const int orig = (bid & 7) * 64 + (bid >> 3);
    const int b   = orig >> 6;
    const int idx = orig & 63;
    const int ct  = idx & 1;
    const int nt  = idx >> 1;
    const int n0  = nt * 128;

    const f32x4 zerov = {0.f, 0.f, 0.f, 0.f};

    // E row owned by this thread (P production)
    const int nl = wid * 16 + col;
    if (tid < 128) sinvLds[tid] = sinvbuf[(size_t)b * N_ + n0 + tid];

    const bf16x8 qf = *(const bf16x8*)(qbf + ((size_t)b * N_ + n0 + nl) * 32 + grp * 8);
    const unsigned short* kbase = kbf + ((size_t)b * N_ + col) * 32 + grp * 8;

    // A (V) staging: pre-swizzled global source, linear LDS dest
    const unsigned short* Vb = vstack + ((size_t)b * 512 + ct * 256) * N_;
    const int q1 = tid + 512;
    const unsigned short* pa0g = Vb + (size_t)(tid >> 2) * N_ + (((tid & 3) ^ ((tid >> 2) & 3)) * 8);
    const unsigned short* pa1g = Vb + (size_t)(q1 >> 2) * N_ + (((q1 & 3) ^ ((q1 >> 2) & 3)) * 8);

    // P write byte-offsets within a ring slot (XOR-swizzled per 16B unit)
    const int bwA = nl * 64 + ((((grp >> 1)) ^ (col & 3)) << 4) + (grp & 1) * 8;
    const int bwB = bwA ^ 32;

    // fragment read byte-offsets
    const int raBase = (wr * 128 + col) * 64 + ((grp ^ (col & 3)) << 4);
    const int rbBase = (wc * 32  + col) * 64 + ((grp ^ (col & 3)) << 4);

    // flush constants: wave flushes rows rlF = ct*64 + wid*8 + (lane>>3),
    // m-chunk mc = lane&7 (fu = mc>>1, fh = mc&1)
    const int fj = lane >> 3;
    const int fu = (lane >> 1) & 3;
    const int fh = lane & 1;
    const int rlF = ct * 64 + wid * 8 + fj;
    const int flOff = rlF * 64 + ((fu ^ (fj & 3)) << 4) + fh * 8;
    float* const attF = att + (size_t)b * N_ * N_ + (size_t)(n0 + rlF) * N_ + (lane & 7) * 4;

    f32x4 acc[8][2];
#pragma unroll
    for (int ai = 0; ai < 8; ++ai)
#pragma unroll
        for (int bj = 0; bj < 2; ++bj)
            acc[ai][bj] = zerov;

#define PACKB(P, BASE, OFF) do {                                              \
    bf16x4 pkv = { (__bf16)(P)[0], (__bf16)(P)[1],                            \
                   (__bf16)(P)[2], (__bf16)(P)[3] };                          \
    *(bf16x4*)((char*)(BASE) + (OFF)) = pkv;                                  \
} while (0)

    // ring pointers
    unsigned short *aC = &AsmR[0][0], *aN = &AsmR[1][0], *aT = &AsmR[2][0];
    unsigned short *pPrev = &Bring[2][0], *pC = &Bring[0][0], *pN = &Bring[1][0];

    // ---- prologue: stage A(0),A(1); k(0),k(1); P(0) -> pC ----
    gld16(pa0g, aC + tid * 8);
    gld16(pa1g, aC + tid * 8 + 4096);
    gld16(pa0g + 32, aN + tid * 8);
    gld16(pa1g + 32, aN + tid * 8 + 4096);
    __builtin_amdgcn_sched_barrier(0);
    bf16x8 kA0, kA1, kB0, kB1;
    kA0 = *(const bf16x8*)kbase;
    kA1 = *(const bf16x8*)(kbase + 512);
    kB0 = *(const bf16x8*)(kbase + 1024);
    kB1 = *(const bf16x8*)(kbase + 1536);
    {
        f32x4 p0 = expv(MF(kA0, qf));
        f32x4 p1 = expv(MF(kA1, qf));
        PACKB(p0, pC, bwA);
        PACKB(p1, pC, bwB);
    }
    asm volatile("s_waitcnt lgkmcnt(0)" ::: "memory");
    __builtin_amdgcn_s_barrier();
    __builtin_amdgcn_sched_barrier(0);
    const float ivF = sinvLds[rlF];

    auto step = [&](const bf16x8& kc0, const bf16x8& kc1,
                    bf16x8& kn0, bf16x8& kn1, int T) {
        // (1) PV fragment reads (A tile T from aC, P tile T from pC)
        bf16x8 bfr[2], af0[4], af1[4];
#pragma unroll
        for (int bj = 0; bj < 2; ++bj)
            bfr[bj] = *(const bf16x8*)((const char*)pC + rbBase + bj * 1024);
#pragma unroll
        for (int ai = 0; ai < 4; ++ai)
            af0[ai] = *(const bf16x8*)((const char*)aC + raBase + ai * 1024);
        // (2) stage A(T+2) (clamped) — first in this step's vmem queue
        const int mt2 = (T + 2 < 128) ? T + 2 : 127;
        gld16(pa0g + (size_t)mt2 * 32, aT + tid * 8);
        gld16(pa1g + (size_t)mt2 * 32, aT + tid * 8 + 4096);
        __builtin_amdgcn_sched_barrier(0);
        // (3) E(T+1) + exp -> pN; load k(T+2) (clamped)
        {
            f32x4 e0 = MF(kc0, qf);
            f32x4 e1 = MF(kc1, qf);
            kn0 = *(const bf16x8*)(kbase + (size_t)mt2 * 1024);
            kn1 = *(const bf16x8*)(kbase + (size_t)mt2 * 1024 + 512);
            f32x4 p0 = expv(e0);
            f32x4 p1 = expv(e1);
            PACKB(p0, pN, bwA);
            PACKB(p1, pN, bwB);
        }
        // (3b) flush tile T-1 from pPrev: one 1KB contiguous store per wave
        if (T > 0) {
            u16x4 pb = *(const u16x4*)((const char*)pPrev + flOff);
            f32x4 pv = { bf2f(pb[0]) * ivF, bf2f(pb[1]) * ivF,
                         bf2f(pb[2]) * ivF, bf2f(pb[3]) * ivF };
            *(f32x4*)(attF + (size_t)(T - 1) * 32) = pv;
        }
        // (4) PV MFMAs
#pragma unroll
        for (int ai = 0; ai < 4; ++ai)
#pragma unroll
            for (int bj = 0; bj < 2; ++bj)
                acc[ai][bj] = __builtin_amdgcn_mfma_f32_16x16x32_bf16(
                    af0[ai], bfr[bj], acc[ai][bj], 0, 0, 0);
#pragma unroll
        for (int ai = 0; ai < 4; ++ai)
            af1[ai] = *(const bf16x8*)((const char*)aC + raBase + (4 + ai) * 1024);
#pragma unroll
        for (int ai = 0; ai < 4; ++ai)
#pragma unroll
            for (int bj = 0; bj < 2; ++bj)
                acc[4 + ai][bj] = __builtin_amdgcn_mfma_f32_16x16x32_bf16(
                    af1[ai], bfr[bj], acc[4 + ai][bj], 0, 0, 0);
        // (5) fence: LDS visibility only — stores stay in flight
        asm volatile("s_waitcnt lgkmcnt(0)" ::: "memory");
        __builtin_amdgcn_s_barrier();
        __builtin_amdgcn_sched_barrier(0);
        // rotate rings
        unsigned short* t1 = aC; aC = aN; aN = aT; aT = t1;
        unsigned short* t2 = pPrev; pPrev = pC; pC = pN; pN = t2;
    };

    for (int tt = 0; tt < 64; ++tt) {
        step(kB0, kB1, kA0, kA1, 2 * tt);
        step(kA0, kA1, kB0, kB1, 2 * tt + 1);
    }

    // ---- epilogue flush: tile 127 (now in pPrev after final rotation) ----
    {
        u16x4 pb = *(const u16x4*)((const char*)pPrev + flOff);
        f32x4 pv = { bf2f(pb[0]) * ivF, bf2f(pb[1]) * ivF,
                     bf2f(pb[2]) * ivF, bf2f(pb[3]) * ivF };
        *(f32x4*)(attF + (size_t)127 * 32) = pv;
    }

    // ---- epilogue: out = acc * inv + x ----
    float* outp     = ct ? out2 : out1;
    const float* xp = ct ? x2 : x1;
    float sc[2];
#pragma unroll
    for (int bj = 0; bj < 2; ++bj)
        sc[bj] = sinvLds[wc * 32 + bj * 16 + col];
#pragma unroll
    for (int ai = 0; ai < 8; ++ai) {
        const int c_l = wr * 128 + ai * 16 + grp * 4;
#pragma unroll
        for (int bj = 0; bj < 2; ++bj) {
            const int n = n0 + wc * 32 + bj * 16 + col;
#pragma unroll
            for (int r = 0; r < 4; ++r) {
                const size_t idx = ((size_t)b * C_ + c_l + r) * N_ + n;
                outp[idx] = acc[ai][bj][r] * sc[bj] + xp[idx];
            }
        }
    }
#undef PACKB
}

// ---------------------------------------------------------------------------
extern "C" void kernel_launch(void* const* d_in, const int* in_sizes, int n_in,
                              void* d_out, int out_size, void* d_ws, size_t ws_size,
                              hipStream_t stream)
{
    const float* x1  = (const float*)d_in[0];
    const float* x2  = (const float*)d_in[1];
    const float* Wq  = (const float*)d_in[2];
    const float* bq  = (const float*)d_in[3];
    const float* Wk  = (const float*)d_in[4];
    const float* bk  = (const float*)d_in[5];
    const float* Wv1 = (const float*)d_in[6];
    const float* bv1 = (const float*)d_in[7];
    const float* Wv2 = (const float*)d_in[8];
    const float* bv2 = (const float*)d_in[9];

    float* out  = (float*)d_out;
    float* out1 = out;
    float* out2 = out + (size_t)B_ * C_ * N_;
    float* att  = out + 2 * (size_t)B_ * C_ * N_;

    // xbfT (32 MB) scribbles the front of the att region; fused_pv
    // fully overwrites all of att afterwards.
    unsigned short* xbfT = (unsigned short*)att;

    char* ws = (char*)d_ws;
    unsigned short* qbf = (unsigned short*)ws;                                  // 2 MB
    unsigned short* kbf = (unsigned short*)(ws + (size_t)2 * 1024 * 1024);      // 2 MB
    unsigned short* vstack = (unsigned short*)(ws + (size_t)4 * 1024 * 1024);   // 32 MB
    float* pq = (float*)(ws + (size_t)36 * 1024 * 1024);                        // 8 MB
    float* pk = (float*)(ws + (size_t)44 * 1024 * 1024);                        // 8 MB
    unsigned short* Wbf = (unsigned short*)(ws + (size_t)52 * 1024 * 1024);     // 256 KB
    float* sinvbuf = (float*)(ws + (size_t)53 * 1024 * 1024);                   // 128 KB

    wconv<<<64, 256, 0, stream>>>(Wv1, Wv2, Wbf);
    qk_part<<<B_ * 16 * 4, 256, 0, stream>>>(x1, x2, Wq, Wk, pq, pk, xbfT);
    qk_reduce<<<(B_ * N_ * 4) / 256, 256, 0, stream>>>(pq, pk, bq, bk, qbf, kbf);
    rowsum<<<B_ * 64, 256, 0, stream>>>(qbf, kbf, sinvbuf);
    v_mfma<<<B_ * 2 * 64, 256, 0, stream>>>(Wbf, xbfT, bv1, bv2, vstack);
    fused_pv<<<512, 512, 0, stream>>>(qbf, kbf, vstack, sinvbuf, x1, x2, out1, out2, att);
}

// Round 11
// 502.881 us; speedup vs baseline: 1.0487x; 1.0085x over previous
//
#include <hip/hip_runtime.h>
#include <hip/hip_bf16.h>

#define B_ 8
#define C_ 256
#define N_ 4096
#define D_ 16
#define TWO_C 512

typedef __bf16 bf16x8 __attribute__((ext_vector_type(8)));
typedef __bf16 bf16x4 __attribute__((ext_vector_type(4)));
typedef float f32x4 __attribute__((ext_vector_type(4)));
typedef unsigned short u16x4 __attribute__((ext_vector_type(4)));

static __device__ __forceinline__ unsigned short f2bf_rtn(float f) {
    unsigned int u = __builtin_bit_cast(unsigned int, f);
    u += 0x7fffu + ((u >> 16) & 1u);
    return (unsigned short)(u >> 16);
}

__device__ __forceinline__ void gld16(const void* g, void* l) {
    __builtin_amdgcn_global_load_lds(
        (const __attribute__((address_space(1))) unsigned int*)g,
        (__attribute__((address_space(3))) unsigned int*)l, 16, 0, 0);
}

__device__ __forceinline__ f32x4 expv(f32x4 e) {
    f32x4 r = { __expf(e[0]), __expf(e[1]), __expf(e[2]), __expf(e[3]) };
    return r;
}

#define MF(K, Q) __builtin_amdgcn_mfma_f32_16x16x32_bf16((K), (Q), zerov, 0, 0, 0)

// ---------------------------------------------------------------------------
// Kernel 0: Wv1/Wv2 -> bf16 stacked [512][256]. grid = 64 blocks of 256.
// ---------------------------------------------------------------------------
__global__ __launch_bounds__(256) void wconv(
    const float* __restrict__ Wv1, const float* __restrict__ Wv2,
    unsigned short* __restrict__ Wbf)
{
    const int i = blockIdx.x * 256 + threadIdx.x;
    f32x4 a = ((const f32x4*)Wv1)[i];
    f32x4 b = ((const f32x4*)Wv2)[i];
    u16x4 ua = { f2bf_rtn(a[0]), f2bf_rtn(a[1]), f2bf_rtn(a[2]), f2bf_rtn(a[3]) };
    u16x4 ub = { f2bf_rtn(b[0]), f2bf_rtn(b[1]), f2bf_rtn(b[2]), f2bf_rtn(b[3]) };
    ((u16x4*)Wbf)[i] = ua;
    ((u16x4*)Wbf)[16384 + i] = ub;
}

// ---------------------------------------------------------------------------
// Kernel 1a: partial q/k over a 128-wide c-chunk + side-write x as bf16
// TRANSPOSED xbfT[b][n][512]. grid = B*16*4 = 512 blocks.
// ---------------------------------------------------------------------------
__global__ __launch_bounds__(256) void qk_part(
    const float* __restrict__ x1, const float* __restrict__ x2,
    const float* __restrict__ Wq, const float* __restrict__ Wk,
    float* __restrict__ pq, float* __restrict__ pk,
    unsigned short* __restrict__ xbfT)
{
    const int tid = threadIdx.x;
    const int bid = blockIdx.x;
    const int ch = bid & 3;
    const int nt = (bid >> 2) & 15;
    const int b  = bid >> 6;
    const int n  = nt * 256 + tid;

    const float* xs  = (ch < 2) ? x1 : x2;
    const int xoff = (ch & 1) * 128;
    const int wcol = ch * 128;

    const float* px = xs + ((size_t)b * C_ + xoff) * N_ + n;
    unsigned short* xT = xbfT + ((size_t)b * N_ + n) * TWO_C + wcol;

    float aq[D_], ak[D_];
#pragma unroll
    for (int d = 0; d < D_; ++d) { aq[d] = 0.f; ak[d] = 0.f; }

    for (int c8 = 0; c8 < 16; ++c8) {
        unsigned short xb[8];
#pragma unroll
        for (int j = 0; j < 8; ++j) {
            const int c = c8 * 8 + j;
            float xv = px[(size_t)c * N_];
            xb[j] = f2bf_rtn(xv);
#pragma unroll
            for (int d = 0; d < D_; ++d) {
                aq[d] += Wq[d * TWO_C + wcol + c] * xv;
                ak[d] += Wk[d * TWO_C + wcol + c] * xv;
            }
        }
        u16x4 lo = { xb[0], xb[1], xb[2], xb[3] };
        u16x4 hi = { xb[4], xb[5], xb[6], xb[7] };
        *(u16x4*)(xT + c8 * 8)     = lo;
        *(u16x4*)(xT + c8 * 8 + 4) = hi;
    }

    f32x4* q4 = (f32x4*)pq + (size_t)ch * B_ * N_ * 4 + ((size_t)b * N_ + n) * 4;
    f32x4* k4 = (f32x4*)pk + (size_t)ch * B_ * N_ * 4 + ((size_t)b * N_ + n) * 4;
#pragma unroll
    for (int j = 0; j < 4; ++j) {
        f32x4 tq = { aq[4*j], aq[4*j+1], aq[4*j+2], aq[4*j+3] };
        f32x4 tk = { ak[4*j], ak[4*j+1], ak[4*j+2], ak[4*j+3] };
        q4[j] = tq;
        k4[j] = tk;
    }
}

// ---------------------------------------------------------------------------
// Kernel 1b: reduce 4 partials + bias, emit bf16 q/k in [B][N][32] layout.
// ---------------------------------------------------------------------------
__global__ __launch_bounds__(256) void qk_reduce(
    const float* __restrict__ pq, const float* __restrict__ pk,
    const float* __restrict__ bq, const float* __restrict__ bk,
    unsigned short* __restrict__ qbf, unsigned short* __restrict__ kbf)
{
    const int tg = blockIdx.x * 256 + threadIdx.x;
    const int row = tg >> 2;
    const int d4  = tg & 3;
    const f32x4* pq4 = (const f32x4*)pq;
    const f32x4* pk4 = (const f32x4*)pk;
    f32x4 q = ((const f32x4*)bq)[d4];
    f32x4 k = ((const f32x4*)bk)[d4];
    const size_t stride = (size_t)B_ * N_ * 4;
#pragma unroll
    for (int ch = 0; ch < 4; ++ch) {
        q += pq4[ch * stride + tg];
        k += pk4[ch * stride + tg];
    }
    u16x4 qo = { f2bf_rtn(q[0]), f2bf_rtn(q[1]), f2bf_rtn(q[2]), f2bf_rtn(q[3]) };
    u16x4 ko = { f2bf_rtn(k[0]), f2bf_rtn(k[1]), f2bf_rtn(k[2]), f2bf_rtn(k[3]) };
    u16x4 z  = { 0, 0, 0, 0 };
    *(u16x4*)(qbf + (size_t)row * 32 + d4 * 4)      = qo;
    *(u16x4*)(qbf + (size_t)row * 32 + 16 + d4 * 4) = z;
    *(u16x4*)(kbf + (size_t)row * 32 + d4 * 4)      = ko;
    *(u16x4*)(kbf + (size_t)row * 32 + 16 + d4 * 4) = z;
}

// ---------------------------------------------------------------------------
// Kernel 2: v = Wv @ x + bv via MFMA, LDS-free. grid = 1024 blocks of 256.
// ---------------------------------------------------------------------------
__global__ __launch_bounds__(256) void v_mfma(
    const unsigned short* __restrict__ Wbf,
    const unsigned short* __restrict__ xbfT,
    const float* __restrict__ bv1, const float* __restrict__ bv2,
    unsigned short* __restrict__ vstack)
{
    const int tid  = threadIdx.x;
    const int lane = tid & 63;
    const int wid  = tid >> 6;
    const int bid  = blockIdx.x;
    const int b    = bid >> 7;
    const int half = (bid >> 6) & 1;
    const int n0   = (bid & 63) * 64;
    const int col  = lane & 15;
    const int grp  = lane >> 4;
    const int koff = grp * 8;

    const unsigned short* pa[4];
    const unsigned short* pb[4];
#pragma unroll
    for (int ai = 0; ai < 4; ++ai)
        pa[ai] = Wbf + (size_t)(half * 256 + wid * 64 + ai * 16 + col) * 256 + koff;
#pragma unroll
    for (int bj = 0; bj < 4; ++bj)
        pb[bj] = xbfT + ((size_t)b * N_ + n0 + bj * 16 + col) * TWO_C + half * 256 + koff;

    f32x4 acc[4][4];
#pragma unroll
    for (int ai = 0; ai < 4; ++ai)
#pragma unroll
        for (int bj = 0; bj < 4; ++bj)
            acc[ai][bj] = (f32x4){0.f, 0.f, 0.f, 0.f};

#pragma unroll
    for (int s = 0; s < 8; ++s) {
        bf16x8 af[4], bfr[4];
#pragma unroll
        for (int ai = 0; ai < 4; ++ai) af[ai] = *(const bf16x8*)(pa[ai] + s * 32);
#pragma unroll
        for (int bj = 0; bj < 4; ++bj) bfr[bj] = *(const bf16x8*)(pb[bj] + s * 32);
#pragma unroll
        for (int ai = 0; ai < 4; ++ai)
#pragma unroll
            for (int bj = 0; bj < 4; ++bj)
                acc[ai][bj] = __builtin_amdgcn_mfma_f32_16x16x32_bf16(
                    af[ai], bfr[bj], acc[ai][bj], 0, 0, 0);
    }

    const float* bias = half ? bv2 : bv1;
#pragma unroll
    for (int ai = 0; ai < 4; ++ai) {
        const int cb = wid * 64 + ai * 16 + grp * 4;
#pragma unroll
        for (int r = 0; r < 4; ++r) {
            const float bv = bias[cb + r];
            unsigned short* vr = vstack + ((size_t)b * 512 + half * 256 + cb + r) * N_;
#pragma unroll
            for (int bj = 0; bj < 4; ++bj)
                vr[n0 + bj * 16 + col] = f2bf_rtn(acc[ai][bj][r] + bv);
        }
    }
}

// ---------------------------------------------------------------------------
// Kernel 2b: rowsum -> sinvbuf[b*N+n] = 1/sum_m exp(e[n][m]).
// grid = B*64 = 512 blocks of 256.
// ---------------------------------------------------------------------------
__global__ __launch_bounds__(256) void rowsum(
    const unsigned short* __restrict__ qbf,
    const unsigned short* __restrict__ kbf,
    float* __restrict__ sinvbuf)
{
    const int tid  = threadIdx.x;
    const int lane = tid & 63;
    const int wid  = tid >> 6;
    const int b  = blockIdx.x >> 6;
    const int n0 = (blockIdx.x & 63) * 64 + wid * 16;
    const int col = lane & 15;
    const int grp = lane >> 4;
    const f32x4 zerov = {0.f, 0.f, 0.f, 0.f};

    const bf16x8 qf = *(const bf16x8*)(qbf + ((size_t)b * N_ + n0 + col) * 32 + grp * 8);
    const unsigned short* kp = kbf + ((size_t)b * N_ + col) * 32 + grp * 8;

    float rs = 0.f;
#pragma unroll 4
    for (int t = 0; t < 128; ++t) {
        bf16x8 k0 = *(const bf16x8*)kp;
        bf16x8 k1 = *(const bf16x8*)(kp + 512);
        kp += 1024;
        f32x4 p0 = expv(MF(k0, qf));
        f32x4 p1 = expv(MF(k1, qf));
        rs += (p0[0] + p0[1]) + (p0[2] + p0[3])
            + (p1[0] + p1[1]) + (p1[2] + p1[3]);
    }
    rs += __shfl_xor(rs, 16);
    rs += __shfl_xor(rs, 32);
    if (lane < 16)
        sinvbuf[(size_t)b * N_ + n0 + col] = 1.f / rs;
}

// ---------------------------------------------------------------------------
// Kernel 3: HETEROGENEOUS fused kernel — two block roles, data-independent,
// co-resident on every CU (LDS 48.5 KB -> 3 blocks/CU; 2 PV + 1 att).
//
// Role PV (slot 0..63 per batch): pure PV pipeline (NO att stores).
//   256c (ct half of stacked V) x 128n tile, A dbuf via global_load_lds,
//   P produced in-register (E MFMA + exp) -> LDS dbuf, 16 PV MFMA/wave/step,
//   fence = vmcnt(2) lgkm(0) + barrier (retires gld16 pair, keeps k-loads).
//
// Role ATT (slot 64..95 per batch): round-3-style streaming attention write.
//   128 n-rows/block, no LDS / no barriers; 8-deep k register ring so the
//   compiler's counted vmcnt keeps ~8 stores/wave in flight; writes
//   att[n][m] = exp(e)*inv as f32x4 (64B/row/iter, contiguous over iters).
//
// blockIdx: b = bid&7 (one batch per XCD), slot = bid>>3 (0..95).
// PV blocks dispatch first (2/CU), att blocks fill the third slot.
// grid = 768 blocks of 512 threads.
// ---------------------------------------------------------------------------
__global__ __launch_bounds__(512) void fused_pv(
    const unsigned short* __restrict__ qbf,
    const unsigned short* __restrict__ kbf,
    const unsigned short* __restrict__ vstack,
    const float* __restrict__ sinvbuf,
    const float* __restrict__ x1, const float* __restrict__ x2,
    float* __restrict__ out1, float* __restrict__ out2,
    float* __restrict__ att)
{
    __shared__ unsigned short Asm[2][256 * 32];   // 32 KB, V dbuf
    __shared__ unsigned short Bsm[2][128 * 32];   // 16 KB, P dbuf
    __shared__ float sinvLds[128];

    const int tid  = threadIdx.x;
    const int lane = tid & 63;
    const int wid  = tid >> 6;
    const int col  = lane & 15;
    const int grp  = lane >> 4;

    const int bid  = blockIdx.x;
    const int b    = bid & 7;      // batch == XCD
    const int slot = bid >> 3;     // 0..95 within batch

    const f32x4 zerov = {0.f, 0.f, 0.f, 0.f};

    if (slot >= 64) {
        // =================== ATT-STREAM ROLE ===================
        const int n0   = (slot - 64) * 128;
        const int nrow = n0 + wid * 16 + col;
        const float inv = sinvbuf[(size_t)b * N_ + nrow];
        const bf16x8 qf = *(const bf16x8*)(qbf + ((size_t)b * N_ + nrow) * 32 + grp * 8);
        const unsigned short* kpb = kbf + ((size_t)b * N_ + col) * 32 + grp * 8;
        float* ap = att + (size_t)b * N_ * N_ + (size_t)nrow * N_ + grp * 4;

        bf16x8 kr[8];
#pragma unroll
        for (int j = 0; j < 8; ++j)
            kr[j] = *(const bf16x8*)(kpb + j * 512);

#pragma unroll 8
        for (int t = 0; t < 248; ++t) {
            f32x4 e = MF(kr[t & 7], qf);
            kr[t & 7] = *(const bf16x8*)(kpb + (size_t)(t + 8) * 512);
            f32x4 p = expv(e) * inv;
            *(f32x4*)(ap + (size_t)t * 16) = p;
        }
#pragma unroll
        for (int t = 248; t < 256; ++t) {
            f32x4 e = MF(kr[t & 7], qf);
            f32x4 p = expv(e) * inv;
            *(f32x4*)(ap + (size_t)t * 16) = p;
        }
        return;
    }

    // =================== PV ROLE ===================
    const int ct = slot >> 5;
    const int nt = slot & 31;
    const int n0 = nt * 128;
    const int wr = wid >> 2;      // 0..1 : c-offset *128
    const int wc = wid & 3;       // 0..3 : n-offset *32

    const int nl = wid * 16 + col;
    if (tid < 128) sinvLds[tid] = sinvbuf[(size_t)b * N_ + n0 + tid];

    const bf16x8 qf = *(const bf16x8*)(qbf + ((size_t)b * N_ + n0 + nl) * 32 + grp * 8);
    const unsigned short* kbase = kbf + ((size_t)b * N_ + col) * 32 + grp * 8;

    // A (V) staging: pre-swizzled global source, linear LDS dest
    const unsigned short* Vb = vstack + ((size_t)b * 512 + ct * 256) * N_;
    const int q1 = tid + 512;
    const unsigned short* pa0g = Vb + (size_t)(tid >> 2) * N_ + (((tid & 3) ^ ((tid >> 2) & 3)) * 8);
    const unsigned short* pa1g = Vb + (size_t)(q1 >> 2) * N_ + (((q1 & 3) ^ ((q1 >> 2) & 3)) * 8);

    // P write byte-offsets within a P buffer (XOR-swizzled per 16B unit)
    const int bwA = nl * 64 + ((((grp >> 1)) ^ (col & 3)) << 4) + (grp & 1) * 8;
    const int bwB = bwA ^ 32;

    // fragment read byte-offsets
    const int raBase = (wr * 128 + col) * 64 + ((grp ^ (col & 3)) << 4);
    const int rbBase = (wc * 32  + col) * 64 + ((grp ^ (col & 3)) << 4);

    f32x4 acc[8][2];
#pragma unroll
    for (int ai = 0; ai < 8; ++ai)
#pragma unroll
        for (int bj = 0; bj < 2; ++bj)
            acc[ai][bj] = zerov;

#define PACKB(P, BASE, OFF) do {                                              \
    bf16x4 pkv = { (__bf16)(P)[0], (__bf16)(P)[1],                            \
                   (__bf16)(P)[2], (__bf16)(P)[3] };                          \
    *(bf16x4*)((char*)(BASE) + (OFF)) = pkv;                                  \
} while (0)

    // ---- prologue: stage A(0); P(0) from k(0); preload kA = k(1) ----
    gld16(pa0g, &Asm[0][tid * 8]);
    gld16(pa1g, &Asm[0][tid * 8 + 4096]);
    __builtin_amdgcn_sched_barrier(0);
    bf16x8 kA0, kA1, kB0, kB1;
    {
        bf16x8 k00 = *(const bf16x8*)kbase;
        bf16x8 k01 = *(const bf16x8*)(kbase + 512);
        kA0 = *(const bf16x8*)(kbase + 1024);
        kA1 = *(const bf16x8*)(kbase + 1536);
        f32x4 p0 = expv(MF(k00, qf));
        f32x4 p1 = expv(MF(k01, qf));
        PACKB(p0, &Bsm[0][0], bwA);
        PACKB(p1, &Bsm[0][0], bwB);
    }
    asm volatile("s_waitcnt vmcnt(2) lgkmcnt(0)" ::: "memory");
    __builtin_amdgcn_s_barrier();
    __builtin_amdgcn_sched_barrier(0);

    auto step = [&](const unsigned short* AsCur, unsigned short* AsNxt,
                    const unsigned short* BsCur, unsigned short* BsNxt,
                    const bf16x8& kc0, const bf16x8& kc1,
                    bf16x8& kn0, bf16x8& kn1, int T) {
        const bool doNext = (T < 127);
        // (1) PV fragment reads (A tile T, P tile T)
        bf16x8 bfr[2], af0[4], af1[4];
#pragma unroll
        for (int bj = 0; bj < 2; ++bj)
            bfr[bj] = *(const bf16x8*)((const char*)BsCur + rbBase + bj * 1024);
#pragma unroll
        for (int ai = 0; ai < 4; ++ai)
            af0[ai] = *(const bf16x8*)((const char*)AsCur + raBase + ai * 1024);
        // (2) stage A(T+1) — pinned first in this step's vmem queue
        if (doNext) {
            gld16(pa0g + (size_t)(T + 1) * 32, AsNxt + tid * 8);
            gld16(pa1g + (size_t)(T + 1) * 32, AsNxt + tid * 8 + 4096);
        }
        __builtin_amdgcn_sched_barrier(0);
        // (3) produce P(T+1) from kc; preload kn = k(T+2)
        if (doNext) {
            f32x4 e0 = MF(kc0, qf);
            f32x4 e1 = MF(kc1, qf);
            if (T < 126) {
                kn0 = *(const bf16x8*)(kbase + (size_t)(T + 2) * 1024);
                kn1 = *(const bf16x8*)(kbase + (size_t)(T + 2) * 1024 + 512);
            }
            f32x4 p0 = expv(e0);
            f32x4 p1 = expv(e1);
            PACKB(p0, BsNxt, bwA);
            PACKB(p1, BsNxt, bwB);
        }
        // (4) PV MFMAs
#pragma unroll
        for (int ai = 0; ai < 4; ++ai)
#pragma unroll
            for (int bj = 0; bj < 2; ++bj)
                acc[ai][bj] = __builtin_amdgcn_mfma_f32_16x16x32_bf16(
                    af0[ai], bfr[bj], acc[ai][bj], 0, 0, 0);
#pragma unroll
        for (int ai = 0; ai < 4; ++ai)
            af1[ai] = *(const bf16x8*)((const char*)AsCur + raBase + (4 + ai) * 1024);
#pragma unroll
        for (int ai = 0; ai < 4; ++ai)
#pragma unroll
            for (int bj = 0; bj < 2; ++bj)
                acc[4 + ai][bj] = __builtin_amdgcn_mfma_f32_16x16x32_bf16(
                    af1[ai], bfr[bj], acc[4 + ai][bj], 0, 0, 0);
        // (5) fence: retires gld16 pair, keeps the 2 k-loads in flight
        if (doNext) {
            asm volatile("s_waitcnt vmcnt(2) lgkmcnt(0)" ::: "memory");
            __builtin_amdgcn_s_barrier();
            __builtin_amdgcn_sched_barrier(0);
        }
    };

    for (int tt = 0; tt < 64; ++tt) {
        step(&Asm[0][0], &Asm[1][0], &Bsm[0][0], &Bsm[1][0], kA0, kA1, kB0, kB1,
             2 * tt);
        step(&Asm[1][0], &Asm[0][0], &Bsm[1][0], &Bsm[0][0], kB0, kB1, kA0, kA1,
             2 * tt + 1);
    }

    // ---- epilogue: out = acc * inv + x ----
    float* outp     = ct ? out2 : out1;
    const float* xp = ct ? x2 : x1;
    float sc[2];
#pragma unroll
    for (int bj = 0; bj < 2; ++bj)
        sc[bj] = sinvLds[wc * 32 + bj * 16 + col];
#pragma unroll
    for (int ai = 0; ai < 8; ++ai) {
        const int c_l = wr * 128 + ai * 16 + grp * 4;
#pragma unroll
        for (int bj = 0; bj < 2; ++bj) {
            const int n = n0 + wc * 32 + bj * 16 + col;
#pragma unroll
            for (int r = 0; r < 4; ++r) {
                const size_t idx = ((size_t)b * C_ + c_l + r) * N_ + n;
                outp[idx] = acc[ai][bj][r] * sc[bj] + xp[idx];
            }
        }
    }
#undef PACKB
}

// ---------------------------------------------------------------------------
extern "C" void kernel_launch(void* const* d_in, const int* in_sizes, int n_in,
                              void* d_out, int out_size, void* d_ws, size_t ws_size,
                              hipStream_t stream)
{
    const float* x1  = (const float*)d_in[0];
    const float* x2  = (const float*)d_in[1];
    const float* Wq  = (const float*)d_in[2];
    const float* bq  = (const float*)d_in[3];
    const float* Wk  = (const float*)d_in[4];
    const float* bk  = (const float*)d_in[5];
    const float* Wv1 = (const float*)d_in[6];
    const float* bv1 = (const float*)d_in[7];
    const float* Wv2 = (const float*)d_in[8];
    const float* bv2 = (const float*)d_in[9];

    float* out  = (float*)d_out;
    float* out1 = out;
    float* out2 = out + (size_t)B_ * C_ * N_;
    float* att  = out + 2 * (size_t)B_ * C_ * N_;

    // xbfT (32 MB) scribbles the front of the att region; fused_pv's att
    // role fully overwrites all of att afterwards.
    unsigned short* xbfT = (unsigned short*)att;

    char* ws = (char*)d_ws;
    unsigned short* qbf = (unsigned short*)ws;                                  // 2 MB
    unsigned short* kbf = (unsigned short*)(ws + (size_t)2 * 1024 * 1024);      // 2 MB
    unsigned short* vstack = (unsigned short*)(ws + (size_t)4 * 1024 * 1024);   // 32 MB
    float* pq = (float*)(ws + (size_t)36 * 1024 * 1024);                        // 8 MB
    float* pk = (float*)(ws + (size_t)44 * 1024 * 1024);                        // 8 MB
    unsigned short* Wbf = (unsigned short*)(ws + (size_t)52 * 1024 * 1024);     // 256 KB
    float* sinvbuf = (float*)(ws + (size_t)53 * 1024 * 1024);                   // 128 KB

    wconv<<<64, 256, 0, stream>>>(Wv1, Wv2, Wbf);
    qk_part<<<B_ * 16 * 4, 256, 0, stream>>>(x1, x2, Wq, Wk, pq, pk, xbfT);
    qk_reduce<<<(B_ * N_ * 4) / 256, 256, 0, stream>>>(pq, pk, bq, bk, qbf, kbf);
    rowsum<<<B_ * 64, 256, 0, stream>>>(qbf, kbf, sinvbuf);
    v_mfma<<<B_ * 2 * 64, 256, 0, stream>>>(Wbf, xbfT, bv1, bv2, vstack);
    fused_pv<<<768, 512, 0, stream>>>(qbf, kbf, vstack, sinvbuf, x1, x2, out1, out2, att);
}

// Round 14
// 481.526 us; speedup vs baseline: 1.0952x; 1.0443x over previous
//
#include <hip/hip_runtime.h>
#include <hip/hip_bf16.h>

#define B_ 8
#define C_ 256
#define N_ 4096
#define D_ 16
#define TWO_C 512

#define ASB 16384            // A slot bytes (256 rows x 32 m x 2B)
#define PSLOT_SHORTS 8224    // 256*32 + 32 pad shorts
#define PSB (PSLOT_SHORTS*2) // 16448 B (pad staggers banks by 16)

typedef __bf16 bf16x8 __attribute__((ext_vector_type(8)));
typedef __bf16 bf16x4 __attribute__((ext_vector_type(4)));
typedef float f32x4 __attribute__((ext_vector_type(4)));
typedef unsigned short u16x4 __attribute__((ext_vector_type(4)));

static __device__ __forceinline__ unsigned short f2bf_rtn(float f) {
    unsigned int u = __builtin_bit_cast(unsigned int, f);
    u += 0x7fffu + ((u >> 16) & 1u);
    return (unsigned short)(u >> 16);
}

static __device__ __forceinline__ float bf2f(unsigned short s) {
    return __builtin_bit_cast(float, (unsigned int)s << 16);
}

__device__ __forceinline__ void gld16(const void* g, void* l) {
    __builtin_amdgcn_global_load_lds(
        (const __attribute__((address_space(1))) unsigned int*)g,
        (__attribute__((address_space(3))) unsigned int*)l, 16, 0, 0);
}

__device__ __forceinline__ f32x4 expv(f32x4 e) {
    f32x4 r = { __expf(e[0]), __expf(e[1]), __expf(e[2]), __expf(e[3]) };
    return r;
}

#define MF(K, Q) __builtin_amdgcn_mfma_f32_16x16x32_bf16((K), (Q), zerov, 0, 0, 0)

// ---------------------------------------------------------------------------
// Kernel 0: Wv1/Wv2 -> bf16 stacked [512][256]. grid = 64 blocks of 256.
// ---------------------------------------------------------------------------
__global__ __launch_bounds__(256) void wconv(
    const float* __restrict__ Wv1, const float* __restrict__ Wv2,
    unsigned short* __restrict__ Wbf)
{
    const int i = blockIdx.x * 256 + threadIdx.x;
    f32x4 a = ((const f32x4*)Wv1)[i];
    f32x4 b = ((const f32x4*)Wv2)[i];
    u16x4 ua = { f2bf_rtn(a[0]), f2bf_rtn(a[1]), f2bf_rtn(a[2]), f2bf_rtn(a[3]) };
    u16x4 ub = { f2bf_rtn(b[0]), f2bf_rtn(b[1]), f2bf_rtn(b[2]), f2bf_rtn(b[3]) };
    ((u16x4*)Wbf)[i] = ua;
    ((u16x4*)Wbf)[16384 + i] = ub;
}

// ---------------------------------------------------------------------------
// Kernel 1a: partial q/k over a 128-wide c-chunk + side-write x as bf16
// TRANSPOSED xbfT[b][n][512]. grid = B*16*4 = 512 blocks.
// ---------------------------------------------------------------------------
__global__ __launch_bounds__(256) void qk_part(
    const float* __restrict__ x1, const float* __restrict__ x2,
    const float* __restrict__ Wq, const float* __restrict__ Wk,
    float* __restrict__ pq, float* __restrict__ pk,
    unsigned short* __restrict__ xbfT)
{
    const int tid = threadIdx.x;
    const int bid = blockIdx.x;
    const int ch = bid & 3;
    const int nt = (bid >> 2) & 15;
    const int b  = bid >> 6;
    const int n  = nt * 256 + tid;

    const float* xs  = (ch < 2) ? x1 : x2;
    const int xoff = (ch & 1) * 128;
    const int wcol = ch * 128;

    const float* px = xs + ((size_t)b * C_ + xoff) * N_ + n;
    unsigned short* xT = xbfT + ((size_t)b * N_ + n) * TWO_C + wcol;

    float aq[D_], ak[D_];
#pragma unroll
    for (int d = 0; d < D_; ++d) { aq[d] = 0.f; ak[d] = 0.f; }

    for (int c8 = 0; c8 < 16; ++c8) {
        unsigned short xb[8];
#pragma unroll
        for (int j = 0; j < 8; ++j) {
            const int c = c8 * 8 + j;
            float xv = px[(size_t)c * N_];
            xb[j] = f2bf_rtn(xv);
#pragma unroll
            for (int d = 0; d < D_; ++d) {
                aq[d] += Wq[d * TWO_C + wcol + c] * xv;
                ak[d] += Wk[d * TWO_C + wcol + c] * xv;
            }
        }
        u16x4 lo = { xb[0], xb[1], xb[2], xb[3] };
        u16x4 hi = { xb[4], xb[5], xb[6], xb[7] };
        *(u16x4*)(xT + c8 * 8)     = lo;
        *(u16x4*)(xT + c8 * 8 + 4) = hi;
    }

    f32x4* q4 = (f32x4*)pq + (size_t)ch * B_ * N_ * 4 + ((size_t)b * N_ + n) * 4;
    f32x4* k4 = (f32x4*)pk + (size_t)ch * B_ * N_ * 4 + ((size_t)b * N_ + n) * 4;
#pragma unroll
    for (int j = 0; j < 4; ++j) {
        f32x4 tq = { aq[4*j], aq[4*j+1], aq[4*j+2], aq[4*j+3] };
        f32x4 tk = { ak[4*j], ak[4*j+1], ak[4*j+2], ak[4*j+3] };
        q4[j] = tq;
        k4[j] = tk;
    }
}

// ---------------------------------------------------------------------------
// Kernel 1b: reduce 4 partials + bias, emit bf16 q/k in [B][N][32] layout.
// ---------------------------------------------------------------------------
__global__ __launch_bounds__(256) void qk_reduce(
    const float* __restrict__ pq, const float* __restrict__ pk,
    const float* __restrict__ bq, const float* __restrict__ bk,
    unsigned short* __restrict__ qbf, unsigned short* __restrict__ kbf)
{
    const int tg = blockIdx.x * 256 + threadIdx.x;
    const int row = tg >> 2;
    const int d4  = tg & 3;
    const f32x4* pq4 = (const f32x4*)pq;
    const f32x4* pk4 = (const f32x4*)pk;
    f32x4 q = ((const f32x4*)bq)[d4];
    f32x4 k = ((const f32x4*)bk)[d4];
    const size_t stride = (size_t)B_ * N_ * 4;
#pragma unroll
    for (int ch = 0; ch < 4; ++ch) {
        q += pq4[ch * stride + tg];
        k += pk4[ch * stride + tg];
    }
    u16x4 qo = { f2bf_rtn(q[0]), f2bf_rtn(q[1]), f2bf_rtn(q[2]), f2bf_rtn(q[3]) };
    u16x4 ko = { f2bf_rtn(k[0]), f2bf_rtn(k[1]), f2bf_rtn(k[2]), f2bf_rtn(k[3]) };
    u16x4 z  = { 0, 0, 0, 0 };
    *(u16x4*)(qbf + (size_t)row * 32 + d4 * 4)      = qo;
    *(u16x4*)(qbf + (size_t)row * 32 + 16 + d4 * 4) = z;
    *(u16x4*)(kbf + (size_t)row * 32 + d4 * 4)      = ko;
    *(u16x4*)(kbf + (size_t)row * 32 + 16 + d4 * 4) = z;
}

// ---------------------------------------------------------------------------
// Kernel 2: v = Wv @ x + bv via MFMA, LDS-free. grid = 1024 blocks of 256.
// ---------------------------------------------------------------------------
__global__ __launch_bounds__(256) void v_mfma(
    const unsigned short* __restrict__ Wbf,
    const unsigned short* __restrict__ xbfT,
    const float* __restrict__ bv1, const float* __restrict__ bv2,
    unsigned short* __restrict__ vstack)
{
    const int tid  = threadIdx.x;
    const int lane = tid & 63;
    const int wid  = tid >> 6;
    const int bid  = blockIdx.x;
    const int b    = bid >> 7;
    const int half = (bid >> 6) & 1;
    const int n0   = (bid & 63) * 64;
    const int col  = lane & 15;
    const int grp  = lane >> 4;
    const int koff = grp * 8;

    const unsigned short* pa[4];
    const unsigned short* pb[4];
#pragma unroll
    for (int ai = 0; ai < 4; ++ai)
        pa[ai] = Wbf + (size_t)(half * 256 + wid * 64 + ai * 16 + col) * 256 + koff;
#pragma unroll
    for (int bj = 0; bj < 4; ++bj)
        pb[bj] = xbfT + ((size_t)b * N_ + n0 + bj * 16 + col) * TWO_C + half * 256 + koff;

    f32x4 acc[4][4];
#pragma unroll
    for (int ai = 0; ai < 4; ++ai)
#pragma unroll
        for (int bj = 0; bj < 4; ++bj)
            acc[ai][bj] = (f32x4){0.f, 0.f, 0.f, 0.f};

#pragma unroll
    for (int s = 0; s < 8; ++s) {
        bf16x8 af[4], bfr[4];
#pragma unroll
        for (int ai = 0; ai < 4; ++ai) af[ai] = *(const bf16x8*)(pa[ai] + s * 32);
#pragma unroll
        for (int bj = 0; bj < 4; ++bj) bfr[bj] = *(const bf16x8*)(pb[bj] + s * 32);
#pragma unroll
        for (int ai = 0; ai < 4; ++ai)
#pragma unroll
            for (int bj = 0; bj < 4; ++bj)
                acc[ai][bj] = __builtin_amdgcn_mfma_f32_16x16x32_bf16(
                    af[ai], bfr[bj], acc[ai][bj], 0, 0, 0);
    }

    const float* bias = half ? bv2 : bv1;
#pragma unroll
    for (int ai = 0; ai < 4; ++ai) {
        const int cb = wid * 64 + ai * 16 + grp * 4;
#pragma unroll
        for (int r = 0; r < 4; ++r) {
            const float bv = bias[cb + r];
            unsigned short* vr = vstack + ((size_t)b * 512 + half * 256 + cb + r) * N_;
#pragma unroll
            for (int bj = 0; bj < 4; ++bj)
                vr[n0 + bj * 16 + col] = f2bf_rtn(acc[ai][bj][r] + bv);
        }
    }
}

// ---------------------------------------------------------------------------
// Kernel 2b: rowsum -> sinvbuf[b*N+n] = 1/sum_m exp(e[n][m]).
// grid = B*64 = 512 blocks of 256.
// ---------------------------------------------------------------------------
__global__ __launch_bounds__(256) void rowsum(
    const unsigned short* __restrict__ qbf,
    const unsigned short* __restrict__ kbf,
    float* __restrict__ sinvbuf)
{
    const int tid  = threadIdx.x;
    const int lane = tid & 63;
    const int wid  = tid >> 6;
    const int b  = blockIdx.x >> 6;
    const int n0 = (blockIdx.x & 63) * 64 + wid * 16;
    const int col = lane & 15;
    const int grp = lane >> 4;
    const f32x4 zerov = {0.f, 0.f, 0.f, 0.f};

    const bf16x8 qf = *(const bf16x8*)(qbf + ((size_t)b * N_ + n0 + col) * 32 + grp * 8);
    const unsigned short* kp = kbf + ((size_t)b * N_ + col) * 32 + grp * 8;

    float rs = 0.f;
#pragma unroll 4
    for (int t = 0; t < 128; ++t) {
        bf16x8 k0 = *(const bf16x8*)kp;
        bf16x8 k1 = *(const bf16x8*)(kp + 512);
        kp += 1024;
        f32x4 p0 = expv(MF(k0, qf));
        f32x4 p1 = expv(MF(k1, qf));
        rs += (p0[0] + p0[1]) + (p0[2] + p0[3])
            + (p1[0] + p1[1]) + (p1[2] + p1[3]);
    }
    rs += __shfl_xor(rs, 16);
    rs += __shfl_xor(rs, 32);
    if (lane < 16)
        sinvbuf[(size_t)b * N_ + n0 + col] = 1.f / rs;
}

// ---------------------------------------------------------------------------
// Kernel 3: FUSED attention + PV, BN=256 (big wave tiles), 6-slot P ring,
// windowed 512B-contiguous att flushes, no-vmcnt fences.
// Tile: 256c (ct half of V) x 256n; 512 thr = 8 waves (2c x 4n), each wave
// 128c x 64n = 32 PV MFMA from 12 ds_read_b128 per step.
// P: each wave produces rows {wid*16+col, +128} (4 E-MFMA, 16 exp, 4 ds_write).
// Rings: A 3-slot (stage T+2 at step T); P 6-slot (produce T+1, consume T,
// flush window T-4..T-1 every 4 steps). Fence = lgkmcnt(0)+barrier ONLY:
// the k(T+2)-register wait each step (FIFO) retires older gld16s; att
// stores are issued last each step -> live >=2 steps, never force-drained.
// Flush: per inst, 2 rows x 512B contiguous (128 m f32 spanning 4 tiles);
// ct0 flushes rows 0-127, ct1 rows 128-255 (n-split; E computed redundantly).
// LDS: 48K (A) + 96.4K (P) + 1K = 145.4 KB -> 1 block/CU, 8 waves.
// grid = 256 (8b x 16nt x 2ct, one batch per XCD), 512 threads.
// ---------------------------------------------------------------------------
__global__ __launch_bounds__(512) void fused_pv(
    const unsigned short* __restrict__ qbf,
    const unsigned short* __restrict__ kbf,
    const unsigned short* __restrict__ vstack,
    const float* __restrict__ sinvbuf,
    const float* __restrict__ x1, const float* __restrict__ x2,
    float* __restrict__ out1, float* __restrict__ out2,
    float* __restrict__ att)
{
    __shared__ unsigned short Ar[3 * (ASB / 2)];       // 48 KB
    __shared__ unsigned short Pr[6 * PSLOT_SHORTS];    // 96.4 KB
    __shared__ float sinvLds[256];

    const int tid  = threadIdx.x;
    const int lane = tid & 63;
    const int wid  = tid >> 6;
    const int wr   = wid >> 2;      // 0..1 : c-offset *128
    const int wc   = wid & 3;       // 0..3 : n-offset *64
    const int col  = lane & 15;
    const int grp  = lane >> 4;

    // XCD swizzle: 32 blocks/XCD = one batch; ct pairs adjacent
    const int bid  = blockIdx.x;
    const int orig = (bid & 7) * 32 + (bid >> 3);
    const int b   = orig >> 5;
    const int idx = orig & 31;
    const int ct  = idx & 1;
    const int nt  = idx >> 1;
    const int n0  = nt * 256;

    const f32x4 zerov = {0.f, 0.f, 0.f, 0.f};

    // P-row ownership: wave produces rows nl and nl+128
    const int nl = wid * 16 + col;
    if (tid < 256) sinvLds[tid] = sinvbuf[(size_t)b * N_ + n0 + tid];

    const bf16x8 qf0 = *(const bf16x8*)(qbf + ((size_t)b * N_ + n0 + nl) * 32 + grp * 8);
    const bf16x8 qf1 = *(const bf16x8*)(qbf + ((size_t)b * N_ + n0 + 128 + nl) * 32 + grp * 8);
    const unsigned short* kbase = kbf + ((size_t)b * N_ + col) * 32 + grp * 8;

    // A (V) staging: pre-swizzled global source, linear LDS dest
    const unsigned short* Vb = vstack + ((size_t)b * 512 + ct * 256) * N_;
    const int q1 = tid + 512;
    const unsigned short* pa0g = Vb + (size_t)(tid >> 2) * N_ + (((tid & 3) ^ ((tid >> 2) & 3)) * 8);
    const unsigned short* pa1g = Vb + (size_t)(q1 >> 2) * N_ + (((q1 & 3) ^ ((q1 >> 2) & 3)) * 8);

    // P write byte-offsets (XOR-swizzled per 16B unit); rows nl, nl+128
    const int bwA = nl * 64 + ((((grp >> 1)) ^ (nl & 3)) << 4) + (grp & 1) * 8;
    const int bwB = bwA ^ 32;

    // PV fragment read byte-offsets
    int raOff[8], rbOff[4];
#pragma unroll
    for (int ai = 0; ai < 8; ++ai) {
        const int ra = wr * 128 + ai * 16 + col;
        raOff[ai] = ra * 64 + ((grp ^ (ra & 3)) << 4);
    }
#pragma unroll
    for (int bj = 0; bj < 4; ++bj) {
        const int rb = wc * 64 + bj * 16 + col;
        rbOff[bj] = rb * 64 + ((grp ^ (rb & 3)) << 4);
    }

    // flush constants: 2 rows/inst x 512B; rows rbase + 2i + (lane>>5)
    const int rbase = ct * 128 + wid * 16;
    const int l31   = lane & 31;
    const int twB   = (l31 >> 3) * PSB;         // tile-in-window -> slot offset
    const int ul    = (lane & 7) >> 1;          // 16B unit within tile row
    const int fh    = lane & 1;
    float* const attL = att + (size_t)b * N_ * N_ + (size_t)n0 * N_ + l31 * 4;

    f32x4 acc[8][4];
#pragma unroll
    for (int ai = 0; ai < 8; ++ai)
#pragma unroll
        for (int bj = 0; bj < 4; ++bj)
            acc[ai][bj] = zerov;

#define PACKB(P, OFF) do {                                                    \
    bf16x4 pkv = { (__bf16)(P)[0], (__bf16)(P)[1],                            \
                   (__bf16)(P)[2], (__bf16)(P)[3] };                          \
    *(bf16x4*)((char*)Pr + (OFF)) = pkv;                                      \
} while (0)

    // ---- prologue: stage A(0),A(1) (per-thread dests); P(0); kB <- k(1) ----
    gld16(pa0g,      (char*)Ar + tid * 16);
    gld16(pa1g,      (char*)Ar + 8192 + tid * 16);
    gld16(pa0g + 32, (char*)Ar + ASB + tid * 16);
    gld16(pa1g + 32, (char*)Ar + ASB + 8192 + tid * 16);
    __builtin_amdgcn_sched_barrier(0);
    bf16x8 kA0, kA1, kB0, kB1;
    {
        bf16x8 k00 = *(const bf16x8*)kbase;
        bf16x8 k01 = *(const bf16x8*)(kbase + 512);
        kB0 = *(const bf16x8*)(kbase + 1024);
        kB1 = *(const bf16x8*)(kbase + 1536);
        f32x4 p00 = expv(MF(k00, qf0));
        f32x4 p01 = expv(MF(k01, qf0));
        f32x4 p10 = expv(MF(k00, qf1));
        f32x4 p11 = expv(MF(k01, qf1));
        PACKB(p00, bwA);
        PACKB(p01, bwB);
        PACKB(p10, bwA + 128 * 64);
        PACKB(p11, bwB + 128 * 64);
    }
    asm volatile("s_waitcnt vmcnt(2) lgkmcnt(0)" ::: "memory");
    __builtin_amdgcn_s_barrier();
    __builtin_amdgcn_sched_barrier(0);

    int aCur = 0;            // byte offset of A slot for tile T
    int pCur = 0;            // byte offset of P slot for tile T

    auto step = [&](const bf16x8& kc0, const bf16x8& kc1,
                    bf16x8& kn0, bf16x8& kn1, int T) {
        // (1) PV fragment reads: A(T), P(T)
        bf16x8 bfr[4], af0[4], af1[4];
#pragma unroll
        for (int bj = 0; bj < 4; ++bj)
            bfr[bj] = *(const bf16x8*)((const char*)Pr + pCur + rbOff[bj]);
#pragma unroll
        for (int ai = 0; ai < 4; ++ai)
            af0[ai] = *(const bf16x8*)((const char*)Ar + aCur + raOff[ai]);
        // (2) stage A(T+2) — first in this step's vmem queue
        if (T < 126) {
            int aStage = aCur + 2 * ASB; if (aStage >= 3 * ASB) aStage -= 3 * ASB;
            gld16(pa0g + (size_t)(T + 2) * 32, (char*)Ar + aStage + tid * 16);
            gld16(pa1g + (size_t)(T + 2) * 32, (char*)Ar + aStage + 8192 + tid * 16);
        }
        __builtin_amdgcn_sched_barrier(0);
        // (3) k(T+2) loads; E(T+1) + exp -> P ring slot (T+1)
        if (T < 127) {
            f32x4 e00 = MF(kc0, qf0);
            f32x4 e01 = MF(kc1, qf0);
            f32x4 e10 = MF(kc0, qf1);
            f32x4 e11 = MF(kc1, qf1);
            if (T < 126) {
                kn0 = *(const bf16x8*)(kbase + (size_t)(T + 2) * 1024);
                kn1 = *(const bf16x8*)(kbase + (size_t)(T + 2) * 1024 + 512);
            }
            int pNxt = pCur + PSB; if (pNxt >= 6 * PSB) pNxt = 0;
            f32x4 p00 = expv(e00), p01 = expv(e01);
            f32x4 p10 = expv(e10), p11 = expv(e11);
            PACKB(p00, pNxt + bwA);
            PACKB(p01, pNxt + bwB);
            PACKB(p10, pNxt + bwA + 128 * 64);
            PACKB(p11, pNxt + bwB + 128 * 64);
        }
        // (3b) flush window [T-4, T-1]: stores issued LAST in vmem order
        if ((T & 3) == 0 && T >= 4) {
            int fB = pCur - 4 * PSB; if (fB < 0) fB += 6 * PSB;
            int sB = fB + twB; if (sB >= 6 * PSB) sB -= 6 * PSB;
            const int W0m = (T - 4) * 32;
#pragma unroll
            for (int i = 0; i < 8; ++i) {
                const int r  = rbase + 2 * i + (lane >> 5);
                const int sw = ((ul ^ (r & 3)) << 4) + fh * 8;
                u16x4 pb = *(const u16x4*)((const char*)Pr + sB + r * 64 + sw);
                const float iv = sinvLds[r];
                f32x4 pv = { bf2f(pb[0]) * iv, bf2f(pb[1]) * iv,
                             bf2f(pb[2]) * iv, bf2f(pb[3]) * iv };
                *(f32x4*)(attL + (size_t)r * N_ + W0m) = pv;
            }
        }
        // (4) PV MFMAs: 32
#pragma unroll
        for (int ai = 0; ai < 4; ++ai)
#pragma unroll
            for (int bj = 0; bj < 4; ++bj)
                acc[ai][bj] = __builtin_amdgcn_mfma_f32_16x16x32_bf16(
                    af0[ai], bfr[bj], acc[ai][bj], 0, 0, 0);
#pragma unroll
        for (int ai = 0; ai < 4; ++ai)
            af1[ai] = *(const bf16x8*)((const char*)Ar + aCur + raOff[4 + ai]);
#pragma unroll
        for (int ai = 0; ai < 4; ++ai)
#pragma unroll
            for (int bj = 0; bj < 4; ++bj)
                acc[4 + ai][bj] = __builtin_amdgcn_mfma_f32_16x16x32_bf16(
                    af1[ai], bfr[bj], acc[4 + ai][bj], 0, 0, 0);
        // (5) fence: LDS visibility only — stores/gld16 ride the FIFO
        asm volatile("s_waitcnt lgkmcnt(0)" ::: "memory");
        __builtin_amdgcn_s_barrier();
        __builtin_amdgcn_sched_barrier(0);
        // rotate rings
        aCur += ASB; if (aCur == 3 * ASB) aCur = 0;
        pCur += PSB; if (pCur == 6 * PSB) pCur = 0;
    };

    for (int tt = 0; tt < 64; ++tt) {
        step(kB0, kB1, kA0, kA1, 2 * tt);
        step(kA0, kA1, kB0, kB1, 2 * tt + 1);
    }

    // ---- epilogue flush: window [124, 127] ----
    {
        int fB = pCur - 4 * PSB; if (fB < 0) fB += 6 * PSB;   // slot of tile 124
        int sB = fB + twB; if (sB >= 6 * PSB) sB -= 6 * PSB;
#pragma unroll
        for (int i = 0; i < 8; ++i) {
            const int r  = rbase + 2 * i + (lane >> 5);
            const int sw = ((ul ^ (r & 3)) << 4) + fh * 8;
            u16x4 pb = *(const u16x4*)((const char*)Pr + sB + r * 64 + sw);
            const float iv = sinvLds[r];
            f32x4 pv = { bf2f(pb[0]) * iv, bf2f(pb[1]) * iv,
                         bf2f(pb[2]) * iv, bf2f(pb[3]) * iv };
            *(f32x4*)(attL + (size_t)r * N_ + 124 * 32) = pv;
        }
    }

    // ---- epilogue: out = acc * inv + x ----
    float* outp     = ct ? out2 : out1;
    const float* xp = ct ? x2 : x1;
    float sc[4];
#pragma unroll
    for (int bj = 0; bj < 4; ++bj)
        sc[bj] = sinvLds[wc * 64 + bj * 16 + col];
#pragma unroll
    for (int ai = 0; ai < 8; ++ai) {
        const int c_l = wr * 128 + ai * 16 + grp * 4;
#pragma unroll
        for (int bj = 0; bj < 4; ++bj) {
            const int n = n0 + wc * 64 + bj * 16 + col;
#pragma unroll
            for (int r = 0; r < 4; ++r) {
                const size_t idx2 = ((size_t)b * C_ + c_l + r) * N_ + n;
                outp[idx2] = acc[ai][bj][r] * sc[bj] + xp[idx2];
            }
        }
    }
#undef PACKB
}

// ---------------------------------------------------------------------------
extern "C" void kernel_launch(void* const* d_in, const int* in_sizes, int n_in,
                              void* d_out, int out_size, void* d_ws, size_t ws_size,
                              hipStream_t stream)
{
    const float* x1  = (const float*)d_in[0];
    const float* x2  = (const float*)d_in[1];
    const float* Wq  = (const float*)d_in[2];
    const float* bq  = (const float*)d_in[3];
    const float* Wk  = (const float*)d_in[4];
    const float* bk  = (const float*)d_in[5];
    const float* Wv1 = (const float*)d_in[6];
    const float* bv1 = (const float*)d_in[7];
    const float* Wv2 = (const float*)d_in[8];
    const float* bv2 = (const float*)d_in[9];

    float* out  = (float*)d_out;
    float* out1 = out;
    float* out2 = out + (size_t)B_ * C_ * N_;
    float* att  = out + 2 * (size_t)B_ * C_ * N_;

    // xbfT (32 MB) scribbles the front of the att region; fused_pv
    // fully overwrites all of att afterwards.
    unsigned short* xbfT = (unsigned short*)att;

    char* ws = (char*)d_ws;
    unsigned short* qbf = (unsigned short*)ws;                                  // 2 MB
    unsigned short* kbf = (unsigned short*)(ws + (size_t)2 * 1024 * 1024);      // 2 MB
    unsigned short* vstack = (unsigned short*)(ws + (size_t)4 * 1024 * 1024);   // 32 MB
    float* pq = (float*)(ws + (size_t)36 * 1024 * 1024);                        // 8 MB
    float* pk = (float*)(ws + (size_t)44 * 1024 * 1024);                        // 8 MB
    unsigned short* Wbf = (unsigned short*)(ws + (size_t)52 * 1024 * 1024);     // 256 KB
    float* sinvbuf = (float*)(ws + (size_t)53 * 1024 * 1024);                   // 128 KB

    wconv<<<64, 256, 0, stream>>>(Wv1, Wv2, Wbf);
    qk_part<<<B_ * 16 * 4, 256, 0, stream>>>(x1, x2, Wq, Wk, pq, pk, xbfT);
    qk_reduce<<<(B_ * N_ * 4) / 256, 256, 0, stream>>>(pq, pk, bq, bk, qbf, kbf);
    rowsum<<<B_ * 64, 256, 0, stream>>>(qbf, kbf, sinvbuf);
    v_mfma<<<B_ * 2 * 64, 256, 0, stream>>>(Wbf, xbfT, bv1, bv2, vstack);
    fused_pv<<<256, 512, 0, stream>>>(qbf, kbf, vstack, sinvbuf, x1, x2, out1, out2, att);
}